// Round 1
// baseline (1234.694 us; speedup 1.0000x reference)
//
#include <hip/hip_runtime.h>
#include <hip/hip_bf16.h>
#include <math.h>

#define DEV static __device__ __forceinline__

typedef unsigned short u16;
typedef __attribute__((ext_vector_type(8))) __bf16 bf16x8;
typedef __attribute__((ext_vector_type(4))) float f32x4;

constexpr int SL  = 2048;   // seq len
constexpr int DM  = 768;    // d_model
constexpr int CC  = 256;    // chunk size = window
constexpr int NC  = 8;      // chunks per seq
constexpr int DH  = 64;     // longformer head dim
constexpr int DFF = 3072;
constexpr int DKM = 768;    // outer-MHA head dim

DEV float b2f(u16 u){ union{float f; unsigned u;} c; c.u = ((unsigned)u)<<16; return c.f; }
DEV u16 f2b(float f){ union{float f; unsigned u;} c; c.f=f; unsigned r=(c.u + 0x7fffu + ((c.u>>16)&1u))>>16; return (u16)r; }

DEV void gld16(u16* lds, const u16* g){
  __builtin_amdgcn_global_load_lds((const __attribute__((address_space(1))) void*)g,
                                   (__attribute__((address_space(3))) void*)lds, 16, 0, 0);
}

// ---------------- reductions ----------------
DEV float wred_sum(float v){
#pragma unroll
  for (int o=32;o;o>>=1) v += __shfl_xor(v,o,64);
  return v;
}
DEV float wred_max(float v){
#pragma unroll
  for (int o=32;o;o>>=1) v = fmaxf(v, __shfl_xor(v,o,64));
  return v;
}
DEV float bred_sum(float v, float* sm){
  v = wred_sum(v);
  if ((threadIdx.x & 63)==0) sm[threadIdx.x>>6] = v;
  __syncthreads();
  float r = sm[0]+sm[1]+sm[2]+sm[3];
  __syncthreads();
  return r;
}
DEV float bred_max(float v, float* sm){
  v = wred_max(v);
  if ((threadIdx.x & 63)==0) sm[threadIdx.x>>6] = v;
  __syncthreads();
  float r = fmaxf(fmaxf(sm[0],sm[1]), fmaxf(sm[2],sm[3]));
  __syncthreads();
  return r;
}

// ---------------- generic bf16 MFMA GEMM ----------------
// C = A[M,K] * Bt[N,K]^T ; fp32 accumulate via v_mfma_f32_16x16x32_bf16
// MODE 0: dense.  1: MHA scores (z=(b,h)).  2: MHA PV.  3: SW scores (z=(b,n,h)).  4: SW PV.
// EPI 0: fp32 out. 1: bf16 out. 2: gelu(tanh)+bf16 out.
template<int BM, int BN, int MODE, int EPI>
__global__ __launch_bounds__(256) void gemm_k(
    const u16* __restrict__ A, const u16* __restrict__ Bt,
    float* __restrict__ Cf, u16* __restrict__ Cb,
    int K, int lda, int ldb, int ldc)
{
  constexpr int BK = 32;
  constexpr int WM = BM/2, WN = BN/2, FM = WM/16, FN = WN/16;
  __shared__ __attribute__((aligned(16))) u16 As[BM*BK];
  __shared__ __attribute__((aligned(16))) u16 Bs[BN*BK];
  const int tid = threadIdx.x, lane = tid & 63, wv = tid >> 6;
  const int wr = wv >> 1, wc = wv & 1;
  const int m0 = blockIdx.x * BM, n0 = blockIdx.y * BN, z = blockIdx.z;

  int bb=0, hh=0, nch=0;
  long long baseA=0, baseB=0;
  if constexpr (MODE==1) { bb=z>>2; hh=z&3; baseA=(long long)bb*SL*3072 + hh*DKM; baseB=baseA; }
  if constexpr (MODE==2) { bb=z>>2; hh=z&3; baseA=(long long)z*SL*SL; baseB=((long long)bb*3072 + hh*DKM)*SL; }
  if constexpr (MODE==3) { bb=z/96; int rr=z%96; nch=rr/12; hh=rr%12;
                           baseA=((long long)bb*SL + nch*CC)*DM + hh*DH; baseB=(long long)bb*SL*DM + hh*DH; }
  if constexpr (MODE==4) { bb=z/96; int rr=z%96; nch=rr/12; hh=rr%12;
                           baseA=(long long)z*CC*768; baseB=((long long)bb*DM + hh*DH)*SL; }

  f32x4 acc[FM][FN] = {};

  for (int kt = 0; kt < K; kt += BK) {
    // ---- stage A tile (global_load_lds, 16B/lane, XOR bank swizzle on source)
#pragma unroll
    for (int t = 0; t < (BM*4)/256; ++t) {
      int cb  = (t*4 + wv)*64;          // wave-uniform chunk base
      int ch  = cb + lane;
      int row = ch >> 2, cp = ch & 3;
      int gp  = cp ^ (row & 3) ^ ((row >> 2) & 1);
      long long ga = baseA + (long long)(m0 + row)*lda + (kt + gp*8);
      gld16(&As[cb*8], A + ga);
    }
    // ---- stage B tile
#pragma unroll
    for (int t = 0; t < (BN*4)/256; ++t) {
      int cb  = (t*4 + wv)*64;
      int ch  = cb + lane;
      int row = ch >> 2, cp = ch & 3;
      int gp  = cp ^ (row & 3) ^ ((row >> 2) & 1);
      long long gb;
      if constexpr (MODE==3) {                       // key rows may be OOB -> clamp (masked later)
        int j = nch*CC - CC + n0 + row;
        j = j < 0 ? 0 : (j > SL-1 ? SL-1 : j);
        gb = baseB + (long long)j*ldb + (kt + gp*8);
      } else if constexpr (MODE==4) {                // K index = key pos, clamp chunk base (P=0 there)
        int jb = nch*CC - CC + kt + gp*8;
        jb = jb < 0 ? 0 : (jb > SL-8 ? SL-8 : jb);
        gb = baseB + (long long)(n0 + row)*ldb + jb;
      } else {
        gb = baseB + (long long)(n0 + row)*ldb + (kt + gp*8);
      }
      gld16(&Bs[cb*8], Bt + gb);
    }
    __syncthreads();
    // ---- fragments + MFMA
    bf16x8 af[FM], bfr[FN];
#pragma unroll
    for (int mi=0; mi<FM; ++mi) {
      int row = wr*WM + mi*16 + (lane & 15);
      int cp  = (lane >> 4) ^ (row & 3) ^ ((row >> 2) & 1);
      af[mi] = *reinterpret_cast<const bf16x8*>(&As[row*BK + cp*8]);
    }
#pragma unroll
    for (int ni=0; ni<FN; ++ni) {
      int row = wc*WN + ni*16 + (lane & 15);
      int cp  = (lane >> 4) ^ (row & 3) ^ ((row >> 2) & 1);
      bfr[ni] = *reinterpret_cast<const bf16x8*>(&Bs[row*BK + cp*8]);
    }
#pragma unroll
    for (int mi=0; mi<FM; ++mi)
#pragma unroll
      for (int ni=0; ni<FN; ++ni)
        acc[mi][ni] = __builtin_amdgcn_mfma_f32_16x16x32_bf16(af[mi], bfr[ni], acc[mi][ni], 0,0,0);
    __syncthreads();
  }

  // ---- epilogue: D layout col=lane&15, row=(lane>>4)*4+r  [m89-verified]
#pragma unroll
  for (int mi=0; mi<FM; ++mi)
#pragma unroll
  for (int ni=0; ni<FN; ++ni)
#pragma unroll
  for (int r=0; r<4; ++r) {
    int m = m0 + wr*WM + mi*16 + ((lane>>4)<<2) + r;
    int n = n0 + wc*WN + ni*16 + (lane & 15);
    float v = acc[mi][ni][r];
    if constexpr (EPI==2) v = 0.5f*v*(1.f + tanhf(0.7978845608f*(v + 0.044715f*v*v*v)));
    long long ci;
    if constexpr (MODE==0) ci = (long long)m*ldc + n;
    if constexpr (MODE==1) ci = (long long)z*SL*SL + (long long)m*SL + n;
    if constexpr (MODE==2) ci = ((long long)bb*SL + m)*3072 + hh*DKM + n;
    if constexpr (MODE==3) ci = (long long)z*CC*768 + (long long)m*768 + n;
    if constexpr (MODE==4) ci = ((long long)bb*SL + nch*CC + m)*DM + hh*DH + n;
    if constexpr (EPI==0) Cf[ci] = v; else Cb[ci] = f2b(v);
  }
}

// ---------------- pointwise / small kernels ----------------
__global__ __launch_bounds__(256) void embed_ln_k(const int* __restrict__ x,
    const float* __restrict__ emb, const float* __restrict__ pos,
    const float* __restrict__ g, const float* __restrict__ bta,
    float* __restrict__ of, u16* __restrict__ ob)
{
  __shared__ float sm[4];
  const int row = blockIdx.x, s = row & (SL-1);
  const long long tok = x[row];
  const float* e = emb + tok*DM;
  const float* p = pos + (long long)s*DM;
  float v[3], su=0.f, sq=0.f;
#pragma unroll
  for (int i=0;i<3;++i){ int d=threadIdx.x+i*256; v[i]=e[d]+p[d]; su+=v[i]; sq+=v[i]*v[i]; }
  su = bred_sum(su, sm); sq = bred_sum(sq, sm);
  float mean = su*(1.f/DM), var = sq*(1.f/DM)-mean*mean, rs = rsqrtf(var+1e-5f);
#pragma unroll
  for (int i=0;i<3;++i){ int d=threadIdx.x+i*256;
    float o = (v[i]-mean)*rs*g[d] + bta[d];
    of[(long long)row*DM+d]=o; ob[(long long)row*DM+d]=f2b(o); }
}

__global__ __launch_bounds__(256) void resid_ln_k(const float* __restrict__ a, const float* __restrict__ c,
    const float* __restrict__ g, const float* __restrict__ bta,
    float* __restrict__ of, u16* __restrict__ ob)
{
  __shared__ float sm[4];
  const long long row = blockIdx.x;
  const float* ra = a + row*DM;
  const float* rc = c + row*DM;
  float v[3], su=0.f, sq=0.f;
#pragma unroll
  for (int i=0;i<3;++i){ int d=threadIdx.x+i*256; v[i]=ra[d]+rc[d]; su+=v[i]; sq+=v[i]*v[i]; }
  su = bred_sum(su, sm); sq = bred_sum(sq, sm);
  float mean = su*(1.f/DM), var = sq*(1.f/DM)-mean*mean, rs = rsqrtf(var+1e-5f);
#pragma unroll
  for (int i=0;i<3;++i){ int d=threadIdx.x+i*256;
    float o = (v[i]-mean)*rs*g[d] + bta[d];
    of[row*DM+d]=o; if (ob) ob[row*DM+d]=f2b(o); }
}

// fp32 [Kd,Nd] -> bf16 [Nd,Kd]
__global__ __launch_bounds__(256) void transp_w_k(const float* __restrict__ W, u16* __restrict__ Wt, int Kd, int Nd)
{
  __shared__ float t[32][33];
  int n0 = blockIdx.x*32, k0 = blockIdx.y*32;
  int lx = threadIdx.x & 31, ly = threadIdx.x >> 5;
#pragma unroll
  for (int i=0;i<4;++i) t[ly+i*8][lx] = W[(long long)(k0+ly+i*8)*Nd + n0+lx];
  __syncthreads();
#pragma unroll
  for (int i=0;i<4;++i) Wt[(long long)(n0+ly+i*8)*Kd + k0+lx] = f2b(t[lx][ly+i*8]);
}

// bf16 [8192,Nc] -> bf16 [B][Nc][SL]   (per-batch transpose for V)
__global__ __launch_bounds__(256) void transp_b_k(const u16* __restrict__ in, u16* __restrict__ out, int Nc)
{
  __shared__ u16 t[32][33];
  int c0 = blockIdx.x*32, r0 = blockIdx.y*32;
  int lx = threadIdx.x & 31, ly = threadIdx.x >> 5;
#pragma unroll
  for (int i=0;i<4;++i) t[ly+i*8][lx] = in[(long long)(r0+ly+i*8)*Nc + c0+lx];
  __syncthreads();
  int b = r0 >> 11, s0 = r0 & (SL-1);
#pragma unroll
  for (int i=0;i<4;++i) out[((long long)b*Nc + c0+ly+i*8)*SL + s0+lx] = t[lx][ly+i*8];
}

// sliding-window softmax, in-place on bf16 scores [z][256][768], z=(b*8+n)*12+h
__global__ __launch_bounds__(256) void sw_softmax_k(u16* __restrict__ sc)
{
  __shared__ float sm[4];
  const int rid = blockIdx.x;
  const int ci = rid & (CC-1);
  const int z  = rid >> 8;
  const int n  = (z/12) & (NC-1);
  u16* row = sc + (long long)z*CC*768 + (long long)ci*768;
  float v[3]; float mx = -3e38f;
#pragma unroll
  for (int i=0;i<3;++i){
    int kj = threadIdx.x + i*256;
    int jj = n*CC - CC + kj;
    int di = ci + CC - kj;
    bool ok = (di <= 256) && (di >= -256) && (jj >= 0) && (jj < SL);
    v[i] = ok ? b2f(row[kj])*0.125f : -3e38f;
    mx = fmaxf(mx, v[i]);
  }
  mx = bred_max(mx, sm);
  float s = 0.f;
#pragma unroll
  for (int i=0;i<3;++i){ v[i] = (v[i] > -1e37f) ? __expf(v[i]-mx) : 0.f; s += v[i]; }
  s = bred_sum(s, sm);
  float inv = 1.f/s;
#pragma unroll
  for (int i=0;i<3;++i){ int kj = threadIdx.x + i*256; row[kj] = f2b(v[i]*inv); }
}

// outer-MHA softmax, in-place on bf16 scores [z][2048][2048], z=b*4+h; key mask x!=0
__global__ __launch_bounds__(256) void mha_softmax_k(u16* __restrict__ sc, const int* __restrict__ x)
{
  __shared__ float sm[4];
  const int rid = blockIdx.x;
  const int qi = rid & (SL-1);
  const int z  = rid >> 11;
  const int b  = z >> 2;
  u16* row = sc + (long long)z*SL*SL + (long long)qi*SL;
  const int* xb = x + b*SL;
  float v[8]; float mx = -3e38f;
#pragma unroll
  for (int i=0;i<8;++i){
    int j = threadIdx.x + i*256;
    bool ok = xb[j] != 0;
    v[i] = ok ? b2f(row[j])*0.0360843918f : -3e38f;   // 1/sqrt(768)
    mx = fmaxf(mx, v[i]);
  }
  mx = bred_max(mx, sm);
  float s = 0.f;
#pragma unroll
  for (int i=0;i<8;++i){ v[i] = (v[i] > -1e37f) ? __expf(v[i]-mx) : 0.f; s += v[i]; }
  s = bred_sum(s, sm);
  float inv = 1.f/s;
#pragma unroll
  for (int i=0;i<8;++i){ int j = threadIdx.x + i*256; row[j] = f2b(v[i]*inv); }
}

__global__ __launch_bounds__(256) void pool_part_k(const float* __restrict__ f, float* __restrict__ pp)
{
  int b = blockIdx.x, ch = blockIdx.y;
  float m0=-3e38f, m1=-3e38f, m2=-3e38f;
  for (int s = ch*128; s < ch*128+128; ++s){
    const float* r = f + ((long long)b*SL + s)*DM;
    m0=fmaxf(m0,r[threadIdx.x]); m1=fmaxf(m1,r[threadIdx.x+256]); m2=fmaxf(m2,r[threadIdx.x+512]);
  }
  float* o = pp + (long long)(b*16+ch)*DM;
  o[threadIdx.x]=m0; o[threadIdx.x+256]=m1; o[threadIdx.x+512]=m2;
}

__global__ __launch_bounds__(256) void pool_red_k(const float* __restrict__ pp, float* __restrict__ out)
{
  int b = blockIdx.x;
#pragma unroll
  for (int i=0;i<3;++i){
    int d = threadIdx.x + i*256;
    float m = -3e38f;
    for (int c=0;c<16;++c) m = fmaxf(m, pp[(long long)(b*16+c)*DM + d]);
    out[(long long)b*DM + d] = m;
  }
}

// ---------------- orchestration ----------------
extern "C" void kernel_launch(void* const* d_in, const int* in_sizes, int n_in,
                              void* d_out, int out_size, void* d_ws, size_t ws_size,
                              hipStream_t stream)
{
  const int*   x      = (const int*)  d_in[0];
  const float* emb    = (const float*)d_in[1];
  const float* pos    = (const float*)d_in[2];
  const float* ln_e_g = (const float*)d_in[3];
  const float* ln_e_b = (const float*)d_in[4];
  const float* lf_wq  = (const float*)d_in[5];
  const float* lf_wk  = (const float*)d_in[6];
  const float* lf_wv  = (const float*)d_in[7];
  const float* lf_wo  = (const float*)d_in[8];
  const float* ln1_g  = (const float*)d_in[9];
  const float* ln1_b  = (const float*)d_in[10];
  const float* w1     = (const float*)d_in[11];
  const float* w2     = (const float*)d_in[12];
  const float* ln2_g  = (const float*)d_in[13];
  const float* ln2_b  = (const float*)d_in[14];
  const float* mha_wq = (const float*)d_in[15];
  const float* mha_wk = (const float*)d_in[16];
  const float* mha_wv = (const float*)d_in[17];
  const float* mha_fc = (const float*)d_in[18];
  const float* mha_ln_g = (const float*)d_in[19];
  const float* mha_ln_b = (const float*)d_in[20];

  const long long R = 8192;           // B*S rows
  float* F0 = (float*)d_ws;           // h / out_lf (fp32)
  float* F1 = F0 + R*DM;              // gemm fp32 out
  float* F2 = F1 + R*DM;              // h2 / final ln
  u16* B0 = (u16*)(F2 + R*DM);        // h bf16 -> attn-out bf16
  u16* B1 = B0 + R*DM;                // q  -> h2 bf16
  u16* B2 = B1 + R*DM;                // k  -> out_lf bf16
  u16* B3 = B2 + R*DM;                // v^T [B][768][SL]
  u16* WT = B3 + R*DM;                // transposed weight scratch (bf16, max 3072x768)
  u16* G1 = WT + (long long)DFF*DM;   // gelu-out -> q_mha -> o_mha
  u16* G2 = G1 + R*DFF;               // k_mha
  u16* G3 = G2 + R*DFF;               // v_mha^T [B][3072][SL]
  u16* SC = G3 + R*DFF;               // scores (SW: 151MB bf16; MHA: 134MB bf16); also v row-major temp
  float* PP = (float*)(SC + (long long)4*12*NC*CC*768);  // pool partials

  dim3 T(256);
  // ---- longformer layer
  embed_ln_k<<<dim3(8192), T, 0, stream>>>(x, emb, pos, ln_e_g, ln_e_b, F0, B0);

  transp_w_k<<<dim3(24,24), T, 0, stream>>>(lf_wq, WT, DM, DM);
  gemm_k<128,128,0,1><<<dim3(64,6,1), T, 0, stream>>>(B0, WT, nullptr, B1, DM, DM, DM, DM);
  transp_w_k<<<dim3(24,24), T, 0, stream>>>(lf_wk, WT, DM, DM);
  gemm_k<128,128,0,1><<<dim3(64,6,1), T, 0, stream>>>(B0, WT, nullptr, B2, DM, DM, DM, DM);
  transp_w_k<<<dim3(24,24), T, 0, stream>>>(lf_wv, WT, DM, DM);
  gemm_k<128,128,0,1><<<dim3(64,6,1), T, 0, stream>>>(B0, WT, nullptr, SC, DM, DM, DM, DM);
  transp_b_k<<<dim3(24,256), T, 0, stream>>>(SC, B3, DM);

  gemm_k<128,128,3,1><<<dim3(2,6,384), T, 0, stream>>>(B1, B2, nullptr, SC, DH, DM, DM, 0);
  sw_softmax_k<<<dim3(98304), T, 0, stream>>>(SC);
  gemm_k<128,64,4,1><<<dim3(2,1,384), T, 0, stream>>>(SC, B3, nullptr, B0, 768, 768, SL, 0);

  transp_w_k<<<dim3(24,24), T, 0, stream>>>(lf_wo, WT, DM, DM);
  gemm_k<128,128,0,0><<<dim3(64,6,1), T, 0, stream>>>(B0, WT, F1, nullptr, DM, DM, DM, DM);
  resid_ln_k<<<dim3(8192), T, 0, stream>>>(F0, F1, ln1_g, ln1_b, F2, B1);

  transp_w_k<<<dim3(96,24), T, 0, stream>>>(w1, WT, DM, DFF);
  gemm_k<128,128,0,2><<<dim3(64,24,1), T, 0, stream>>>(B1, WT, nullptr, G1, DM, DM, DM, DFF);
  transp_w_k<<<dim3(24,96), T, 0, stream>>>(w2, WT, DFF, DM);
  gemm_k<128,128,0,0><<<dim3(64,6,1), T, 0, stream>>>(G1, WT, F1, nullptr, DFF, DFF, DFF, DM);
  resid_ln_k<<<dim3(8192), T, 0, stream>>>(F2, F1, ln2_g, ln2_b, F0, B2);

  // ---- outer MHA
  transp_w_k<<<dim3(96,24), T, 0, stream>>>(mha_wq, WT, DM, DFF);
  gemm_k<128,128,0,1><<<dim3(64,24,1), T, 0, stream>>>(B2, WT, nullptr, G1, DM, DM, DM, DFF);
  transp_w_k<<<dim3(96,24), T, 0, stream>>>(mha_wk, WT, DM, DFF);
  gemm_k<128,128,0,1><<<dim3(64,24,1), T, 0, stream>>>(B2, WT, nullptr, G2, DM, DM, DM, DFF);
  transp_w_k<<<dim3(96,24), T, 0, stream>>>(mha_wv, WT, DM, DFF);
  gemm_k<128,128,0,1><<<dim3(64,24,1), T, 0, stream>>>(B2, WT, nullptr, SC, DM, DM, DM, DFF);
  transp_b_k<<<dim3(96,256), T, 0, stream>>>(SC, G3, DFF);

  gemm_k<128,128,1,1><<<dim3(16,16,16), T, 0, stream>>>(G1, G2, nullptr, SC, DKM, 3072, 3072, 0);
  mha_softmax_k<<<dim3(32768), T, 0, stream>>>(SC, x);
  gemm_k<128,128,2,1><<<dim3(16,6,16), T, 0, stream>>>(SC, G3, nullptr, G1, SL, SL, SL, 0);

  transp_w_k<<<dim3(24,96), T, 0, stream>>>(mha_fc, WT, DFF, DM);
  gemm_k<128,128,0,0><<<dim3(64,6,1), T, 0, stream>>>(G1, WT, F1, nullptr, DFF, DFF, DFF, DM);
  resid_ln_k<<<dim3(8192), T, 0, stream>>>(F0, F1, mha_ln_g, mha_ln_b, F2, nullptr);

  pool_part_k<<<dim3(4,16), T, 0, stream>>>(F2, PP);
  pool_red_k<<<dim3(4), T, 0, stream>>>(PP, (float*)d_out);
}

// Round 3
// 1176.491 us; speedup vs baseline: 1.0495x; 1.0495x over previous
//
#include <hip/hip_runtime.h>
#include <hip/hip_bf16.h>
#include <math.h>

#define DEV static __device__ __forceinline__

typedef unsigned short u16;
typedef __attribute__((ext_vector_type(8))) __bf16 bf16x8;
typedef __attribute__((ext_vector_type(4))) float f32x4;

constexpr int SL  = 2048;   // seq len
constexpr int DM  = 768;    // d_model
constexpr int CC  = 256;    // chunk size = window
constexpr int NC  = 8;      // chunks per seq
constexpr int DH  = 64;     // longformer head dim
constexpr int DFF = 3072;
constexpr int DKM = 768;    // outer-MHA head dim

DEV float b2f(u16 u){ union{float f; unsigned u;} c; c.u = ((unsigned)u)<<16; return c.f; }
DEV u16 f2b(float f){ union{float f; unsigned u;} c; c.f=f; unsigned r=(c.u + 0x7fffu + ((c.u>>16)&1u))>>16; return (u16)r; }

DEV void gld16(u16* lds, const u16* g){
  __builtin_amdgcn_global_load_lds((const __attribute__((address_space(1))) void*)g,
                                   (__attribute__((address_space(3))) void*)lds, 16, 0, 0);
}

// ---------------- reductions ----------------
DEV float wred_sum(float v){
#pragma unroll
  for (int o=32;o;o>>=1) v += __shfl_xor(v,o,64);
  return v;
}
DEV float wred_max(float v){
#pragma unroll
  for (int o=32;o;o>>=1) v = fmaxf(v, __shfl_xor(v,o,64));
  return v;
}
DEV float bred_sum(float v, float* sm){
  v = wred_sum(v);
  if ((threadIdx.x & 63)==0) sm[threadIdx.x>>6] = v;
  __syncthreads();
  float r = sm[0]+sm[1]+sm[2]+sm[3];
  __syncthreads();
  return r;
}
DEV float bred_max(float v, float* sm){
  v = wred_max(v);
  if ((threadIdx.x & 63)==0) sm[threadIdx.x>>6] = v;
  __syncthreads();
  float r = fmaxf(fmaxf(sm[0],sm[1]), fmaxf(sm[2],sm[3]));
  __syncthreads();
  return r;
}

// ================= 256x256 8-phase BK=64 MFMA GEMM =================
// C = A[M,K] * Bt[N,K]^T, fp32 accum, bf16 inputs.
// MODE 0: dense.  1: MHA scores (z=(b,h)).  2: MHA PV (z=(b,h)).
// EPI 0: fp32 out. 1: bf16 out. 2: fast-gelu + bf16 out.
// 8 waves (2m x 4n), wave tile 128x64, acc 8x4 f32x4.
// LDS 128 KiB dynamic: As[2][256][64], Bs[2][256][64] bf16, chunk-XOR swizzle.
// A staging halves are INTERLEAVED (rounds {h, h+2}) so that stage-half0 ==
// exactly the rows Q0 reads ([0,64)u[128,192)) and stage-half1 == Q2's rows.
// (Round-2 bug: contiguous halves let Q1's stage of tile t+2 overwrite rows
// [64,128) before wr=0 waves read them in Q2.)
#define MFMA_PH(MH, NH) \
  { _Pragma("unroll") for (int mi2=0; mi2<4; ++mi2) { \
      _Pragma("unroll") for (int ni2=0; ni2<2; ++ni2) { \
        acc[(MH)*4+mi2][(NH)*2+ni2] = __builtin_amdgcn_mfma_f32_16x16x32_bf16(Af[mi2][0], Bf[(NH)*2+ni2][0], acc[(MH)*4+mi2][(NH)*2+ni2], 0,0,0); \
        acc[(MH)*4+mi2][(NH)*2+ni2] = __builtin_amdgcn_mfma_f32_16x16x32_bf16(Af[mi2][1], Bf[(NH)*2+ni2][1], acc[(MH)*4+mi2][(NH)*2+ni2], 0,0,0); } } }

#define PHASE_SYNC \
  __builtin_amdgcn_s_barrier(); \
  asm volatile("s_waitcnt lgkmcnt(0)" ::: "memory"); \
  __builtin_amdgcn_sched_barrier(0); \
  __builtin_amdgcn_s_setprio(1);
#define PHASE_END \
  __builtin_amdgcn_s_setprio(0); \
  __builtin_amdgcn_s_barrier();

template<int MODE, int EPI>
__global__ __launch_bounds__(512,2) void gemm256_k(
    const u16* __restrict__ A, const u16* __restrict__ Bt,
    float* __restrict__ Cf, u16* __restrict__ Cb,
    int K, int lda, int ldb, int ldc)
{
  extern __shared__ u16 lds_dyn[];           // [2][256][64] A | [2][256][64] B
  const int tid = threadIdx.x, lane = tid & 63, wv = tid >> 6;
  const int wr = wv >> 2, wc = wv & 3;
  const int m0 = blockIdx.x * 256, n0 = blockIdx.y * 256, z = blockIdx.z;
  const int nt = K >> 6;                     // K-tiles (>= 12 for all users)

  int bb = 0, hh = 0;
  long long baseA = 0, baseB = 0;
  if constexpr (MODE==1) { bb=z>>2; hh=z&3; baseA=(long long)bb*SL*3072 + hh*DKM; baseB=baseA; }
  if constexpr (MODE==2) { bb=z>>2; hh=z&3; baseA=(long long)z*SL*SL; baseB=((long long)bb*3072 + hh*DKM)*SL; }

  // staging per-thread constants: chunk = 8 bf16 (16B); 8 chunks/row; 512 chunks/round
  const int rb = (wv*64 + lane) >> 3;        // row base within a 64-row round
  const int sg = ((lane & 7) ^ (rb & 7)) * 8;// source chunk offset (swizzle inverse), u16
  // fragment-read per-thread constants (slot = chunk ^ (row&7); row&7 == lane&7 here)
  const int rd0 = (lane & 15)*64 + (((lane>>4) ^ (lane & 7)) * 8);
  const int rd1 = rd0 ^ 32;                  // k-slice 1 = chunk+4 -> slot^4

  auto stageA = [&](int buf, int half, int kt) {
#pragma unroll
    for (int tt = 0; tt < 2; ++tt) {
      const int t = half + tt*2;             // INTERLEAVED halves: h0={0,2}, h1={1,3}
      gld16(lds_dyn + buf*16384 + t*4096 + wv*512,
            A + baseA + (long long)(m0 + t*64 + rb)*lda + (long long)kt*64 + sg);
    }
  };
  auto stageB = [&](int buf, int half, int kt) {
#pragma unroll
    for (int tt = 0; tt < 2; ++tt) {
      const int t = half*2 + tt;             // contiguous (all B reads finish by end of Q1)
      gld16(lds_dyn + 32768 + buf*16384 + t*4096 + wv*512,
            Bt + baseB + (long long)(n0 + t*64 + rb)*ldb + (long long)kt*64 + sg);
    }
  };

  f32x4 acc[8][4] = {};
  bf16x8 Af[4][2];    // current m-half fragments
  bf16x8 Bf[4][2];    // all 4 n-fragments

  // ---- prologue: tile0 fully (4 halves), tile1 {A-h0,B-lo,B-hi}; vmcnt(6) -> tile0 resident
  stageA(0,0,0); stageB(0,0,0); stageB(0,1,0); stageA(0,1,0);
  stageA(1,0,1); stageB(1,0,1); stageB(1,1,1);
  asm volatile("s_waitcnt vmcnt(6)" ::: "memory");
  __builtin_amdgcn_s_barrier();

  for (int t = 0; t < nt; ++t) {
    const int d = t & 1;
    const u16* As_d = lds_dyn + d*16384;
    const u16* Bs_d = lds_dyn + 32768 + d*16384;
    // ---- Q0: read A rows wr*128+[0,64) + B rows wc*64+[0,32); stage A-h1(t+1)
#pragma unroll
    for (int mi2=0; mi2<4; ++mi2) {
      const u16* p = As_d + (wr*128 + mi2*16)*64;
      Af[mi2][0] = *(const bf16x8*)(p + rd0);
      Af[mi2][1] = *(const bf16x8*)(p + rd1);
    }
#pragma unroll
    for (int ni2=0; ni2<2; ++ni2) {
      const u16* p = Bs_d + (wc*64 + ni2*16)*64;
      Bf[ni2][0] = *(const bf16x8*)(p + rd0);
      Bf[ni2][1] = *(const bf16x8*)(p + rd1);
    }
    if (t+1 < nt) stageA(d^1, 1, t+1);
    PHASE_SYNC; MFMA_PH(0,0); PHASE_END;
    // ---- Q1: read B rows wc*64+32+[0,32); stage A-h0(t+2) (rows Q0 just read)
#pragma unroll
    for (int ni2=0; ni2<2; ++ni2) {
      const u16* p = Bs_d + (wc*64 + 32 + ni2*16)*64;
      Bf[2+ni2][0] = *(const bf16x8*)(p + rd0);
      Bf[2+ni2][1] = *(const bf16x8*)(p + rd1);
    }
    if (t+2 < nt) stageA(d, 0, t+2);
    PHASE_SYNC; MFMA_PH(0,1); PHASE_END;
    // ---- Q2: read A rows wr*128+64+[0,64); stage B-lo(t+2)
#pragma unroll
    for (int mi2=0; mi2<4; ++mi2) {
      const u16* p = As_d + (wr*128 + 64 + mi2*16)*64;
      Af[mi2][0] = *(const bf16x8*)(p + rd0);
      Af[mi2][1] = *(const bf16x8*)(p + rd1);
    }
    if (t+2 < nt) stageB(d, 0, t+2);
    PHASE_SYNC; MFMA_PH(1,0); PHASE_END;
    // ---- Q3: no reads; stage B-hi(t+2); counted vmcnt at tile boundary
    if (t+2 < nt) stageB(d, 1, t+2);
    __builtin_amdgcn_s_barrier();
    __builtin_amdgcn_s_setprio(1);
    MFMA_PH(1,1);
    __builtin_amdgcn_s_setprio(0);
    if (t+2 < nt)      { asm volatile("s_waitcnt vmcnt(6)" ::: "memory"); }
    else if (t+1 < nt) { asm volatile("s_waitcnt vmcnt(0)" ::: "memory"); }
    __builtin_amdgcn_s_barrier();
  }

  // ---- epilogue: D layout col=lane&15, row=(lane>>4)*4+r  [m89-verified]
#pragma unroll
  for (int mi=0; mi<8; ++mi)
#pragma unroll
  for (int ni=0; ni<4; ++ni)
#pragma unroll
  for (int r=0; r<4; ++r) {
    int m = m0 + wr*128 + mi*16 + ((lane>>4)<<2) + r;
    int n = n0 + wc*64  + ni*16 + (lane & 15);
    float v = acc[mi][ni][r];
    if constexpr (EPI==2) {
      float u = 0.7978845608f*(v + 0.044715f*v*v*v);
      float th = 1.f - 2.f/(__expf(2.f*u)+1.f);
      v = 0.5f*v*(1.f + th);
    }
    long long ci;
    if constexpr (MODE==0) ci = (long long)m*ldc + n;
    if constexpr (MODE==1) ci = (long long)z*SL*SL + (long long)m*SL + n;
    if constexpr (MODE==2) ci = ((long long)bb*SL + m)*3072 + hh*DKM + n;
    if constexpr (EPI==0) Cf[ci] = v; else Cb[ci] = f2b(v);
  }
}

// ---------------- legacy 128x128 BK=32 GEMM (sliding-window modes only) ----------------
// MODE 3: SW scores (z=(b,n,h)).  4: SW PV.
template<int BM, int BN, int MODE, int EPI>
__global__ __launch_bounds__(256) void gemm_k(
    const u16* __restrict__ A, const u16* __restrict__ Bt,
    float* __restrict__ Cf, u16* __restrict__ Cb,
    int K, int lda, int ldb, int ldc)
{
  constexpr int BK = 32;
  constexpr int WM = BM/2, WN = BN/2, FM = WM/16, FN = WN/16;
  __shared__ __attribute__((aligned(16))) u16 As[BM*BK];
  __shared__ __attribute__((aligned(16))) u16 Bs[BN*BK];
  const int tid = threadIdx.x, lane = tid & 63, wv = tid >> 6;
  const int wr = wv >> 1, wc = wv & 1;
  const int m0 = blockIdx.x * BM, n0 = blockIdx.y * BN, z = blockIdx.z;

  int bb=0, hh=0, nch=0;
  long long baseA=0, baseB=0;
  if constexpr (MODE==3) { bb=z/96; int rr=z%96; nch=rr/12; hh=rr%12;
                           baseA=((long long)bb*SL + nch*CC)*DM + hh*DH; baseB=(long long)bb*SL*DM + hh*DH; }
  if constexpr (MODE==4) { bb=z/96; int rr=z%96; nch=rr/12; hh=rr%12;
                           baseA=(long long)z*CC*768; baseB=((long long)bb*DM + hh*DH)*SL; }

  f32x4 acc[FM][FN] = {};

  for (int kt = 0; kt < K; kt += BK) {
#pragma unroll
    for (int t = 0; t < (BM*4)/256; ++t) {
      int cb  = (t*4 + wv)*64;
      int ch  = cb + lane;
      int row = ch >> 2, cp = ch & 3;
      int gp  = cp ^ (row & 3) ^ ((row >> 2) & 1);
      long long ga = baseA + (long long)(m0 + row)*lda + (kt + gp*8);
      gld16(&As[cb*8], A + ga);
    }
#pragma unroll
    for (int t = 0; t < (BN*4)/256; ++t) {
      int cb  = (t*4 + wv)*64;
      int ch  = cb + lane;
      int row = ch >> 2, cp = ch & 3;
      int gp  = cp ^ (row & 3) ^ ((row >> 2) & 1);
      long long gb;
      if constexpr (MODE==3) {
        int j = nch*CC - CC + n0 + row;
        j = j < 0 ? 0 : (j > SL-1 ? SL-1 : j);
        gb = baseB + (long long)j*ldb + (kt + gp*8);
      } else if constexpr (MODE==4) {
        int jb = nch*CC - CC + kt + gp*8;
        jb = jb < 0 ? 0 : (jb > SL-8 ? SL-8 : jb);
        gb = baseB + (long long)(n0 + row)*ldb + jb;
      } else {
        gb = baseB + (long long)(n0 + row)*ldb + (kt + gp*8);
      }
      gld16(&Bs[cb*8], Bt + gb);
    }
    __syncthreads();
    bf16x8 af[FM], bfr[FN];
#pragma unroll
    for (int mi=0; mi<FM; ++mi) {
      int row = wr*WM + mi*16 + (lane & 15);
      int cp  = (lane >> 4) ^ (row & 3) ^ ((row >> 2) & 1);
      af[mi] = *reinterpret_cast<const bf16x8*>(&As[row*BK + cp*8]);
    }
#pragma unroll
    for (int ni=0; ni<FN; ++ni) {
      int row = wc*WN + ni*16 + (lane & 15);
      int cp  = (lane >> 4) ^ (row & 3) ^ ((row >> 2) & 1);
      bfr[ni] = *reinterpret_cast<const bf16x8*>(&Bs[row*BK + cp*8]);
    }
#pragma unroll
    for (int mi=0; mi<FM; ++mi)
#pragma unroll
      for (int ni=0; ni<FN; ++ni)
        acc[mi][ni] = __builtin_amdgcn_mfma_f32_16x16x32_bf16(af[mi], bfr[ni], acc[mi][ni], 0,0,0);
    __syncthreads();
  }

#pragma unroll
  for (int mi=0; mi<FM; ++mi)
#pragma unroll
  for (int ni=0; ni<FN; ++ni)
#pragma unroll
  for (int r=0; r<4; ++r) {
    int m = m0 + wr*WM + mi*16 + ((lane>>4)<<2) + r;
    int n = n0 + wc*WN + ni*16 + (lane & 15);
    float v = acc[mi][ni][r];
    long long ci = 0;
    if constexpr (MODE==3) ci = (long long)z*CC*768 + (long long)m*768 + n;
    if constexpr (MODE==4) ci = ((long long)bb*SL + nch*CC + m)*DM + hh*DH + n;
    if constexpr (EPI==0) Cf[ci] = v; else Cb[ci] = f2b(v);
  }
}

// ---------------- pointwise / small kernels ----------------
__global__ __launch_bounds__(256) void embed_ln_k(const int* __restrict__ x,
    const float* __restrict__ emb, const float* __restrict__ pos,
    const float* __restrict__ g, const float* __restrict__ bta,
    float* __restrict__ of, u16* __restrict__ ob)
{
  __shared__ float sm[4];
  const int row = blockIdx.x, s = row & (SL-1);
  const long long tok = x[row];
  const float* e = emb + tok*DM;
  const float* p = pos + (long long)s*DM;
  float v[3], su=0.f, sq=0.f;
#pragma unroll
  for (int i=0;i<3;++i){ int d=threadIdx.x+i*256; v[i]=e[d]+p[d]; su+=v[i]; sq+=v[i]*v[i]; }
  su = bred_sum(su, sm); sq = bred_sum(sq, sm);
  float mean = su*(1.f/DM), var = sq*(1.f/DM)-mean*mean, rs = rsqrtf(var+1e-5f);
#pragma unroll
  for (int i=0;i<3;++i){ int d=threadIdx.x+i*256;
    float o = (v[i]-mean)*rs*g[d] + bta[d];
    of[(long long)row*DM+d]=o; ob[(long long)row*DM+d]=f2b(o); }
}

__global__ __launch_bounds__(256) void resid_ln_k(const float* __restrict__ a, const float* __restrict__ c,
    const float* __restrict__ g, const float* __restrict__ bta,
    float* __restrict__ of, u16* __restrict__ ob)
{
  __shared__ float sm[4];
  const long long row = blockIdx.x;
  const float* ra = a + row*DM;
  const float* rc = c + row*DM;
  float v[3], su=0.f, sq=0.f;
#pragma unroll
  for (int i=0;i<3;++i){ int d=threadIdx.x+i*256; v[i]=ra[d]+rc[d]; su+=v[i]; sq+=v[i]*v[i]; }
  su = bred_sum(su, sm); sq = bred_sum(sq, sm);
  float mean = su*(1.f/DM), var = sq*(1.f/DM)-mean*mean, rs = rsqrtf(var+1e-5f);
#pragma unroll
  for (int i=0;i<3;++i){ int d=threadIdx.x+i*256;
    float o = (v[i]-mean)*rs*g[d] + bta[d];
    of[row*DM+d]=o; if (ob) ob[row*DM+d]=f2b(o); }
}

// fp32 [Kd,Nd] -> bf16 [Nd,Kd]
__global__ __launch_bounds__(256) void transp_w_k(const float* __restrict__ W, u16* __restrict__ Wt, int Kd, int Nd)
{
  __shared__ float t[32][33];
  int n0 = blockIdx.x*32, k0 = blockIdx.y*32;
  int lx = threadIdx.x & 31, ly = threadIdx.x >> 5;
#pragma unroll
  for (int i=0;i<4;++i) t[ly+i*8][lx] = W[(long long)(k0+ly+i*8)*Nd + n0+lx];
  __syncthreads();
#pragma unroll
  for (int i=0;i<4;++i) Wt[(long long)(n0+ly+i*8)*Kd + k0+lx] = f2b(t[lx][ly+i*8]);
}

// bf16 [8192,Nc] -> bf16 [B][Nc][SL]
__global__ __launch_bounds__(256) void transp_b_k(const u16* __restrict__ in, u16* __restrict__ out, int Nc)
{
  __shared__ u16 t[32][33];
  int c0 = blockIdx.x*32, r0 = blockIdx.y*32;
  int lx = threadIdx.x & 31, ly = threadIdx.x >> 5;
#pragma unroll
  for (int i=0;i<4;++i) t[ly+i*8][lx] = in[(long long)(r0+ly+i*8)*Nc + c0+lx];
  __syncthreads();
  int b = r0 >> 11, s0 = r0 & (SL-1);
#pragma unroll
  for (int i=0;i<4;++i) out[((long long)b*Nc + c0+ly+i*8)*SL + s0+lx] = t[lx][ly+i*8];
}

// sliding-window softmax, in-place on bf16 scores [z][256][768], z=(b*8+n)*12+h
__global__ __launch_bounds__(256) void sw_softmax_k(u16* __restrict__ sc)
{
  __shared__ float sm[4];
  const int rid = blockIdx.x;
  const int ci = rid & (CC-1);
  const int z  = rid >> 8;
  const int n  = (z/12) & (NC-1);
  u16* row = sc + (long long)z*CC*768 + (long long)ci*768;
  float v[3]; float mx = -3e38f;
#pragma unroll
  for (int i=0;i<3;++i){
    int kj = threadIdx.x + i*256;
    int jj = n*CC - CC + kj;
    int di = ci + CC - kj;
    bool ok = (di <= 256) && (di >= -256) && (jj >= 0) && (jj < SL);
    v[i] = ok ? b2f(row[kj])*0.125f : -3e38f;
    mx = fmaxf(mx, v[i]);
  }
  mx = bred_max(mx, sm);
  float s = 0.f;
#pragma unroll
  for (int i=0;i<3;++i){ v[i] = (v[i] > -1e37f) ? __expf(v[i]-mx) : 0.f; s += v[i]; }
  s = bred_sum(s, sm);
  float inv = 1.f/s;
#pragma unroll
  for (int i=0;i<3;++i){ int kj = threadIdx.x + i*256; row[kj] = f2b(v[i]*inv); }
}

// outer-MHA softmax, in-place on bf16 scores [z][2048][2048], z=b*4+h; key mask x!=0
__global__ __launch_bounds__(256) void mha_softmax_k(u16* __restrict__ sc, const int* __restrict__ x)
{
  __shared__ float sm[4];
  const int rid = blockIdx.x;
  const int qi = rid & (SL-1);
  const int z  = rid >> 11;
  const int b  = z >> 2;
  u16* row = sc + (long long)z*SL*SL + (long long)qi*SL;
  const int* xb = x + b*SL;
  float v[8]; float mx = -3e38f;
#pragma unroll
  for (int i=0;i<8;++i){
    int j = threadIdx.x + i*256;
    bool ok = xb[j] != 0;
    v[i] = ok ? b2f(row[j])*0.0360843918f : -3e38f;   // 1/sqrt(768)
    mx = fmaxf(mx, v[i]);
  }
  mx = bred_max(mx, sm);
  float s = 0.f;
#pragma unroll
  for (int i=0;i<8;++i){ v[i] = (v[i] > -1e37f) ? __expf(v[i]-mx) : 0.f; s += v[i]; }
  s = bred_sum(s, sm);
  float inv = 1.f/s;
#pragma unroll
  for (int i=0;i<8;++i){ int j = threadIdx.x + i*256; row[j] = f2b(v[i]*inv); }
}

__global__ __launch_bounds__(256) void pool_part_k(const float* __restrict__ f, float* __restrict__ pp)
{
  int b = blockIdx.x, ch = blockIdx.y;
  float m0=-3e38f, m1=-3e38f, m2=-3e38f;
  for (int s = ch*128; s < ch*128+128; ++s){
    const float* r = f + ((long long)b*SL + s)*DM;
    m0=fmaxf(m0,r[threadIdx.x]); m1=fmaxf(m1,r[threadIdx.x+256]); m2=fmaxf(m2,r[threadIdx.x+512]);
  }
  float* o = pp + (long long)(b*16+ch)*DM;
  o[threadIdx.x]=m0; o[threadIdx.x+256]=m1; o[threadIdx.x+512]=m2;
}

__global__ __launch_bounds__(256) void pool_red_k(const float* __restrict__ pp, float* __restrict__ out)
{
  int b = blockIdx.x;
#pragma unroll
  for (int i=0;i<3;++i){
    int d = threadIdx.x + i*256;
    float m = -3e38f;
    for (int c=0;c<16;++c) m = fmaxf(m, pp[(long long)(b*16+c)*DM + d]);
    out[(long long)b*DM + d] = m;
  }
}

// ---------------- orchestration ----------------
extern "C" void kernel_launch(void* const* d_in, const int* in_sizes, int n_in,
                              void* d_out, int out_size, void* d_ws, size_t ws_size,
                              hipStream_t stream)
{
  const int*   x      = (const int*)  d_in[0];
  const float* emb    = (const float*)d_in[1];
  const float* pos    = (const float*)d_in[2];
  const float* ln_e_g = (const float*)d_in[3];
  const float* ln_e_b = (const float*)d_in[4];
  const float* lf_wq  = (const float*)d_in[5];
  const float* lf_wk  = (const float*)d_in[6];
  const float* lf_wv  = (const float*)d_in[7];
  const float* lf_wo  = (const float*)d_in[8];
  const float* ln1_g  = (const float*)d_in[9];
  const float* ln1_b  = (const float*)d_in[10];
  const float* w1     = (const float*)d_in[11];
  const float* w2     = (const float*)d_in[12];
  const float* ln2_g  = (const float*)d_in[13];
  const float* ln2_b  = (const float*)d_in[14];
  const float* mha_wq = (const float*)d_in[15];
  const float* mha_wk = (const float*)d_in[16];
  const float* mha_wv = (const float*)d_in[17];
  const float* mha_fc = (const float*)d_in[18];
  const float* mha_ln_g = (const float*)d_in[19];
  const float* mha_ln_b = (const float*)d_in[20];

  // allow 128 KiB dynamic LDS on the 8-phase GEMM instantiations (idempotent)
  (void)hipFuncSetAttribute((const void*)gemm256_k<0,0>, hipFuncAttributeMaxDynamicSharedMemorySize, 131072);
  (void)hipFuncSetAttribute((const void*)gemm256_k<0,1>, hipFuncAttributeMaxDynamicSharedMemorySize, 131072);
  (void)hipFuncSetAttribute((const void*)gemm256_k<0,2>, hipFuncAttributeMaxDynamicSharedMemorySize, 131072);
  (void)hipFuncSetAttribute((const void*)gemm256_k<1,1>, hipFuncAttributeMaxDynamicSharedMemorySize, 131072);
  (void)hipFuncSetAttribute((const void*)gemm256_k<2,1>, hipFuncAttributeMaxDynamicSharedMemorySize, 131072);

  const long long R = 8192;           // B*S rows
  float* F0 = (float*)d_ws;           // h / out_lf (fp32)
  float* F1 = F0 + R*DM;              // gemm fp32 out
  float* F2 = F1 + R*DM;              // h2 / final ln
  u16* B0 = (u16*)(F2 + R*DM);        // h bf16 -> attn-out bf16
  u16* B1 = B0 + R*DM;                // q  -> h2 bf16
  u16* B2 = B1 + R*DM;                // k  -> out_lf bf16
  u16* B3 = B2 + R*DM;                // v^T [B][768][SL]
  u16* WT = B3 + R*DM;                // transposed weight scratch (bf16, max 3072x768)
  u16* G1 = WT + (long long)DFF*DM;   // gelu-out -> q_mha -> o_mha
  u16* G2 = G1 + R*DFF;               // k_mha
  u16* G3 = G2 + R*DFF;               // v_mha^T [B][3072][SL]
  u16* SC = G3 + R*DFF;               // scores scratch; also v row-major temp
  float* PP = (float*)(SC + (long long)4*12*NC*CC*768);  // pool partials

  dim3 T(256), T5(512);
  const size_t SMEM = 131072;
  // ---- longformer layer
  embed_ln_k<<<dim3(8192), T, 0, stream>>>(x, emb, pos, ln_e_g, ln_e_b, F0, B0);

  transp_w_k<<<dim3(24,24), T, 0, stream>>>(lf_wq, WT, DM, DM);
  gemm256_k<0,1><<<dim3(32,3,1), T5, SMEM, stream>>>(B0, WT, nullptr, B1, DM, DM, DM, DM);
  transp_w_k<<<dim3(24,24), T, 0, stream>>>(lf_wk, WT, DM, DM);
  gemm256_k<0,1><<<dim3(32,3,1), T5, SMEM, stream>>>(B0, WT, nullptr, B2, DM, DM, DM, DM);
  transp_w_k<<<dim3(24,24), T, 0, stream>>>(lf_wv, WT, DM, DM);
  gemm256_k<0,1><<<dim3(32,3,1), T5, SMEM, stream>>>(B0, WT, nullptr, SC, DM, DM, DM, DM);
  transp_b_k<<<dim3(24,256), T, 0, stream>>>(SC, B3, DM);

  gemm_k<128,128,3,1><<<dim3(2,6,384), T, 0, stream>>>(B1, B2, nullptr, SC, DH, DM, DM, 0);
  sw_softmax_k<<<dim3(98304), T, 0, stream>>>(SC);
  gemm_k<128,64,4,1><<<dim3(2,1,384), T, 0, stream>>>(SC, B3, nullptr, B0, 768, 768, SL, 0);

  transp_w_k<<<dim3(24,24), T, 0, stream>>>(lf_wo, WT, DM, DM);
  gemm256_k<0,0><<<dim3(32,3,1), T5, SMEM, stream>>>(B0, WT, F1, nullptr, DM, DM, DM, DM);
  resid_ln_k<<<dim3(8192), T, 0, stream>>>(F0, F1, ln1_g, ln1_b, F2, B1);

  transp_w_k<<<dim3(96,24), T, 0, stream>>>(w1, WT, DM, DFF);
  gemm256_k<0,2><<<dim3(32,12,1), T5, SMEM, stream>>>(B1, WT, nullptr, G1, DM, DM, DM, DFF);
  transp_w_k<<<dim3(24,96), T, 0, stream>>>(w2, WT, DFF, DM);
  gemm256_k<0,0><<<dim3(32,3,1), T5, SMEM, stream>>>(G1, WT, F1, nullptr, DFF, DFF, DFF, DM);
  resid_ln_k<<<dim3(8192), T, 0, stream>>>(F2, F1, ln2_g, ln2_b, F0, B2);

  // ---- outer MHA
  transp_w_k<<<dim3(96,24), T, 0, stream>>>(mha_wq, WT, DM, DFF);
  gemm256_k<0,1><<<dim3(32,12,1), T5, SMEM, stream>>>(B2, WT, nullptr, G1, DM, DM, DM, DFF);
  transp_w_k<<<dim3(96,24), T, 0, stream>>>(mha_wk, WT, DM, DFF);
  gemm256_k<0,1><<<dim3(32,12,1), T5, SMEM, stream>>>(B2, WT, nullptr, G2, DM, DM, DM, DFF);
  transp_w_k<<<dim3(96,24), T, 0, stream>>>(mha_wv, WT, DM, DFF);
  gemm256_k<0,1><<<dim3(32,12,1), T5, SMEM, stream>>>(B2, WT, nullptr, SC, DM, DM, DM, DFF);
  transp_b_k<<<dim3(96,256), T, 0, stream>>>(SC, G3, DFF);

  gemm256_k<1,1><<<dim3(8,8,16), T5, SMEM, stream>>>(G1, G2, nullptr, SC, DKM, 3072, 3072, 0);
  mha_softmax_k<<<dim3(32768), T, 0, stream>>>(SC, x);
  gemm256_k<2,1><<<dim3(8,3,16), T5, SMEM, stream>>>(SC, G3, nullptr, G1, SL, SL, SL, 0);

  transp_w_k<<<dim3(24,96), T, 0, stream>>>(mha_fc, WT, DFF, DM);
  gemm256_k<0,0><<<dim3(32,3,1), T5, SMEM, stream>>>(G1, WT, F1, nullptr, DFF, DFF, DFF, DM);
  resid_ln_k<<<dim3(8192), T, 0, stream>>>(F0, F1, mha_ln_g, mha_ln_b, F2, nullptr);

  pool_part_k<<<dim3(4,16), T, 0, stream>>>(F2, PP);
  pool_red_k<<<dim3(4), T, 0, stream>>>(PP, (float*)d_out);
}

// Round 4
// 1039.539 us; speedup vs baseline: 1.1877x; 1.1317x over previous
//
#include <hip/hip_runtime.h>
#include <hip/hip_bf16.h>
#include <math.h>

#define DEV static __device__ __forceinline__

typedef unsigned short u16;
typedef __attribute__((ext_vector_type(8))) __bf16 bf16x8;
typedef __attribute__((ext_vector_type(4))) float f32x4;

constexpr int SL  = 2048;   // seq len
constexpr int DM  = 768;    // d_model
constexpr int CC  = 256;    // chunk size = window
constexpr int NC  = 8;      // chunks per seq
constexpr int DH  = 64;     // longformer head dim
constexpr int DFF = 3072;
constexpr int DKM = 768;    // outer-MHA head dim

DEV float b2f(u16 u){ union{float f; unsigned u;} c; c.u = ((unsigned)u)<<16; return c.f; }
DEV u16 f2b(float f){ union{float f; unsigned u;} c; c.f=f; unsigned r=(c.u + 0x7fffu + ((c.u>>16)&1u))>>16; return (u16)r; }

DEV void gld16(u16* lds, const u16* g){
  __builtin_amdgcn_global_load_lds((const __attribute__((address_space(1))) void*)g,
                                   (__attribute__((address_space(3))) void*)lds, 16, 0, 0);
}

// ---------------- reductions ----------------
DEV float wred_sum(float v){
#pragma unroll
  for (int o=32;o;o>>=1) v += __shfl_xor(v,o,64);
  return v;
}
DEV float wred_max(float v){
#pragma unroll
  for (int o=32;o;o>>=1) v = fmaxf(v, __shfl_xor(v,o,64));
  return v;
}
DEV float bred_sum(float v, float* sm){
  v = wred_sum(v);
  if ((threadIdx.x & 63)==0) sm[threadIdx.x>>6] = v;
  __syncthreads();
  float r = sm[0]+sm[1]+sm[2]+sm[3];
  __syncthreads();
  return r;
}
DEV float bred_max(float v, float* sm){
  v = wred_max(v);
  if ((threadIdx.x & 63)==0) sm[threadIdx.x>>6] = v;
  __syncthreads();
  float r = fmaxf(fmaxf(sm[0],sm[1]), fmaxf(sm[2],sm[3]));
  __syncthreads();
  return r;
}

// ================= 256x256 8-phase BK=64 MFMA GEMM =================
// C = A[M,K] * Bt[N,K]^T, fp32 accum, bf16 inputs.
// MODE 0: dense.  1: MHA scores (z=(b,h)).  2: MHA PV (z=(b,h)).
// EPI 0: fp32 out. 1: bf16 out. 2: fast-gelu + bf16 out. 3: *1/sqrt(768) + bf16.
// Use ONLY when grid >= ~256 blocks (per-block round time ~26-100us).
#define MFMA_PH(MH, NH) \
  { _Pragma("unroll") for (int mi2=0; mi2<4; ++mi2) { \
      _Pragma("unroll") for (int ni2=0; ni2<2; ++ni2) { \
        acc[(MH)*4+mi2][(NH)*2+ni2] = __builtin_amdgcn_mfma_f32_16x16x32_bf16(Af[mi2][0], Bf[(NH)*2+ni2][0], acc[(MH)*4+mi2][(NH)*2+ni2], 0,0,0); \
        acc[(MH)*4+mi2][(NH)*2+ni2] = __builtin_amdgcn_mfma_f32_16x16x32_bf16(Af[mi2][1], Bf[(NH)*2+ni2][1], acc[(MH)*4+mi2][(NH)*2+ni2], 0,0,0); } } }

#define PHASE_SYNC \
  __builtin_amdgcn_s_barrier(); \
  asm volatile("s_waitcnt lgkmcnt(0)" ::: "memory"); \
  __builtin_amdgcn_sched_barrier(0); \
  __builtin_amdgcn_s_setprio(1);
#define PHASE_END \
  __builtin_amdgcn_s_setprio(0); \
  __builtin_amdgcn_s_barrier();

template<int MODE, int EPI>
__global__ __launch_bounds__(512,2) void gemm256_k(
    const u16* __restrict__ A, const u16* __restrict__ Bt,
    float* __restrict__ Cf, u16* __restrict__ Cb,
    int K, int lda, int ldb, int ldc)
{
  extern __shared__ u16 lds_dyn[];           // [2][256][64] A | [2][256][64] B
  const int tid = threadIdx.x, lane = tid & 63, wv = tid >> 6;
  const int wr = wv >> 2, wc = wv & 3;
  const int m0 = blockIdx.x * 256, n0 = blockIdx.y * 256, z = blockIdx.z;
  const int nt = K >> 6;

  int bb = 0, hh = 0;
  long long baseA = 0, baseB = 0;
  if constexpr (MODE==1) { bb=z>>2; hh=z&3; baseA=(long long)bb*SL*3072 + hh*DKM; baseB=baseA; }
  if constexpr (MODE==2) { bb=z>>2; hh=z&3; baseA=(long long)z*SL*SL; baseB=((long long)bb*3072 + hh*DKM)*SL; }

  const int rb = (wv*64 + lane) >> 3;
  const int sg = ((lane & 7) ^ (rb & 7)) * 8;
  const int rd0 = (lane & 15)*64 + (((lane>>4) ^ (lane & 7)) * 8);
  const int rd1 = rd0 ^ 32;

  auto stageA = [&](int buf, int half, int kt) {
#pragma unroll
    for (int tt = 0; tt < 2; ++tt) {
      const int t = half + tt*2;             // INTERLEAVED halves: h0={0,2}, h1={1,3}
      gld16(lds_dyn + buf*16384 + t*4096 + wv*512,
            A + baseA + (long long)(m0 + t*64 + rb)*lda + (long long)kt*64 + sg);
    }
  };
  auto stageB = [&](int buf, int half, int kt) {
#pragma unroll
    for (int tt = 0; tt < 2; ++tt) {
      const int t = half*2 + tt;
      gld16(lds_dyn + 32768 + buf*16384 + t*4096 + wv*512,
            Bt + baseB + (long long)(n0 + t*64 + rb)*ldb + (long long)kt*64 + sg);
    }
  };

  f32x4 acc[8][4] = {};
  bf16x8 Af[4][2];
  bf16x8 Bf[4][2];

  stageA(0,0,0); stageB(0,0,0); stageB(0,1,0); stageA(0,1,0);
  stageA(1,0,1); stageB(1,0,1); stageB(1,1,1);
  asm volatile("s_waitcnt vmcnt(6)" ::: "memory");
  __builtin_amdgcn_s_barrier();

  for (int t = 0; t < nt; ++t) {
    const int d = t & 1;
    const u16* As_d = lds_dyn + d*16384;
    const u16* Bs_d = lds_dyn + 32768 + d*16384;
#pragma unroll
    for (int mi2=0; mi2<4; ++mi2) {
      const u16* p = As_d + (wr*128 + mi2*16)*64;
      Af[mi2][0] = *(const bf16x8*)(p + rd0);
      Af[mi2][1] = *(const bf16x8*)(p + rd1);
    }
#pragma unroll
    for (int ni2=0; ni2<2; ++ni2) {
      const u16* p = Bs_d + (wc*64 + ni2*16)*64;
      Bf[ni2][0] = *(const bf16x8*)(p + rd0);
      Bf[ni2][1] = *(const bf16x8*)(p + rd1);
    }
    if (t+1 < nt) stageA(d^1, 1, t+1);
    PHASE_SYNC; MFMA_PH(0,0); PHASE_END;
#pragma unroll
    for (int ni2=0; ni2<2; ++ni2) {
      const u16* p = Bs_d + (wc*64 + 32 + ni2*16)*64;
      Bf[2+ni2][0] = *(const bf16x8*)(p + rd0);
      Bf[2+ni2][1] = *(const bf16x8*)(p + rd1);
    }
    if (t+2 < nt) stageA(d, 0, t+2);
    PHASE_SYNC; MFMA_PH(0,1); PHASE_END;
#pragma unroll
    for (int mi2=0; mi2<4; ++mi2) {
      const u16* p = As_d + (wr*128 + 64 + mi2*16)*64;
      Af[mi2][0] = *(const bf16x8*)(p + rd0);
      Af[mi2][1] = *(const bf16x8*)(p + rd1);
    }
    if (t+2 < nt) stageB(d, 0, t+2);
    PHASE_SYNC; MFMA_PH(1,0); PHASE_END;
    if (t+2 < nt) stageB(d, 1, t+2);
    __builtin_amdgcn_s_barrier();
    __builtin_amdgcn_s_setprio(1);
    MFMA_PH(1,1);
    __builtin_amdgcn_s_setprio(0);
    if (t+2 < nt)      { asm volatile("s_waitcnt vmcnt(6)" ::: "memory"); }
    else if (t+1 < nt) { asm volatile("s_waitcnt vmcnt(0)" ::: "memory"); }
    __builtin_amdgcn_s_barrier();
  }

#pragma unroll
  for (int mi=0; mi<8; ++mi)
#pragma unroll
  for (int ni=0; ni<4; ++ni)
#pragma unroll
  for (int r=0; r<4; ++r) {
    int m = m0 + wr*128 + mi*16 + ((lane>>4)<<2) + r;
    int n = n0 + wc*64  + ni*16 + (lane & 15);
    float v = acc[mi][ni][r];
    if constexpr (EPI==2) {
      float u = 0.7978845608f*(v + 0.044715f*v*v*v);
      float th = 1.f - 2.f/(__expf(2.f*u)+1.f);
      v = 0.5f*v*(1.f + th);
    }
    if constexpr (EPI==3) v *= 0.0360843918f;   // 1/sqrt(768)
    long long ci;
    if constexpr (MODE==0) ci = (long long)m*ldc + n;
    if constexpr (MODE==1) ci = (long long)z*SL*SL + (long long)m*SL + n;
    if constexpr (MODE==2) ci = ((long long)bb*SL + m)*3072 + hh*DKM + n;
    if constexpr (EPI==0) Cf[ci] = v; else Cb[ci] = f2b(v);
  }
}

// ---------------- legacy 128x128 BK=32 GEMM (narrow-N dense: full-CU grids) ----------------
template<int BM, int BN, int MODE, int EPI>
__global__ __launch_bounds__(256) void gemm_k(
    const u16* __restrict__ A, const u16* __restrict__ Bt,
    float* __restrict__ Cf, u16* __restrict__ Cb,
    int K, int lda, int ldb, int ldc)
{
  constexpr int BK = 32;
  constexpr int WM = BM/2, WN = BN/2, FM = WM/16, FN = WN/16;
  __shared__ __attribute__((aligned(16))) u16 As[BM*BK];
  __shared__ __attribute__((aligned(16))) u16 Bs[BN*BK];
  const int tid = threadIdx.x, lane = tid & 63, wv = tid >> 6;
  const int wr = wv >> 1, wc = wv & 1;
  const int m0 = blockIdx.x * BM, n0 = blockIdx.y * BN;

  f32x4 acc[FM][FN] = {};

  for (int kt = 0; kt < K; kt += BK) {
#pragma unroll
    for (int t = 0; t < (BM*4)/256; ++t) {
      int cb  = (t*4 + wv)*64;
      int ch  = cb + lane;
      int row = ch >> 2, cp = ch & 3;
      int gp  = cp ^ (row & 3) ^ ((row >> 2) & 1);
      long long ga = (long long)(m0 + row)*lda + (kt + gp*8);
      gld16(&As[cb*8], A + ga);
    }
#pragma unroll
    for (int t = 0; t < (BN*4)/256; ++t) {
      int cb  = (t*4 + wv)*64;
      int ch  = cb + lane;
      int row = ch >> 2, cp = ch & 3;
      int gp  = cp ^ (row & 3) ^ ((row >> 2) & 1);
      long long gb = (long long)(n0 + row)*ldb + (kt + gp*8);
      gld16(&Bs[cb*8], Bt + gb);
    }
    __syncthreads();
    bf16x8 af[FM], bfr[FN];
#pragma unroll
    for (int mi=0; mi<FM; ++mi) {
      int row = wr*WM + mi*16 + (lane & 15);
      int cp  = (lane >> 4) ^ (row & 3) ^ ((row >> 2) & 1);
      af[mi] = *reinterpret_cast<const bf16x8*>(&As[row*BK + cp*8]);
    }
#pragma unroll
    for (int ni=0; ni<FN; ++ni) {
      int row = wc*WN + ni*16 + (lane & 15);
      int cp  = (lane >> 4) ^ (row & 3) ^ ((row >> 2) & 1);
      bfr[ni] = *reinterpret_cast<const bf16x8*>(&Bs[row*BK + cp*8]);
    }
#pragma unroll
    for (int mi=0; mi<FM; ++mi)
#pragma unroll
      for (int ni=0; ni<FN; ++ni)
        acc[mi][ni] = __builtin_amdgcn_mfma_f32_16x16x32_bf16(af[mi], bfr[ni], acc[mi][ni], 0,0,0);
    __syncthreads();
  }

#pragma unroll
  for (int mi=0; mi<FM; ++mi)
#pragma unroll
  for (int ni=0; ni<FN; ++ni)
#pragma unroll
  for (int r=0; r<4; ++r) {
    int m = m0 + wr*WM + mi*16 + ((lane>>4)<<2) + r;
    int n = n0 + wc*WN + ni*16 + (lane & 15);
    float v = acc[mi][ni][r];
    long long ci = (long long)m*ldc + n;
    if constexpr (EPI==0) Cf[ci] = v; else Cb[ci] = f2b(v);
  }
}

// ================= fused sliding-window attention =================
// One block = (b, h, 128 q-rows). 4 waves x 32 q-rows. 10 kv-steps of 64 keys
// (clipped at seq edges; steps are 64-aligned so never partially OOB).
// Q in registers; K [key][dim] and V^T [dim][key] staged in swizzled LDS;
// scores in D-layout; online softmax via 16-lane-group shfl; P through
// per-wave swizzled LDS to A-frag layout; PV accumulates O in D-layout.
__global__ __launch_bounds__(256) void sw_attn_k(
    const u16* __restrict__ Qm, const u16* __restrict__ Km,
    const u16* __restrict__ Vt, u16* __restrict__ Om)
{
  __shared__ __attribute__((aligned(16))) u16 Kb_s[64*64];
  __shared__ __attribute__((aligned(16))) u16 Vb_s[64*64];
  __shared__ __attribute__((aligned(16))) u16 Pb_s[4*32*64];
  const int tid = threadIdx.x, lane = tid & 63, wv = tid >> 6;
  const int qc = blockIdx.x >> 1, half = blockIdx.x & 1;
  const int h = blockIdx.y, b = blockIdx.z;
  const int q0 = qc*256 + half*128 + wv*32;        // seq pos of wave's first q row
  const long long rowbase = (long long)b*SL;

  // Q fragments (A-layout: row=lane&15, k-chunk=(lane>>4)*8 + ks*32)
  bf16x8 Qf[2][2];
#pragma unroll
  for (int mi=0;mi<2;++mi)
#pragma unroll
    for (int ks=0;ks<2;++ks)
      Qf[mi][ks] = *(const bf16x8*)(Qm + (rowbase + q0 + mi*16 + (lane&15))*DM + h*DH + ks*32 + (lane>>4)*8);

  f32x4 accO[2][4] = {};
  float mrun[2][4], lrun[2][4];
#pragma unroll
  for (int mi=0;mi<2;++mi)
#pragma unroll
    for (int r=0;r<4;++r){ mrun[mi][r]=-3e38f; lrun[mi][r]=0.f; }

  // staging constants: 16B/thread, 8 chunks per 64-elem row, 32 rows per issue
  const int srow = tid >> 3;               // 0..31
  const int schunk = (tid & 7) ^ (srow & 7);

  const int kb0 = qc*256 + half*128 - 256;
  const int slo = kb0 < 0 ? ((-kb0) >> 6) : 0;
  const int shi_t = (SL - kb0) >> 6;
  const int shi = shi_t < 10 ? shi_t : 10;

  const int qpb = q0 + ((lane>>4)<<2);     // q pos base for (mi=0, r=0)

  for (int s = slo; s < shi; ++s) {
    const int kb = kb0 + s*64;
    // ---- stage K rows [kb, kb+64) and V^T dims (all in-bounds by construction)
#pragma unroll
    for (int ii=0; ii<2; ++ii) {
      gld16(Kb_s + ii*2048 + wv*512,
            Km + (rowbase + kb + srow + ii*32)*DM + h*DH + schunk*8);
      gld16(Vb_s + ii*2048 + wv*512,
            Vt + ((long long)b*DM + h*DH + srow + ii*32)*SL + kb + schunk*8);
    }
    asm volatile("s_waitcnt vmcnt(0)" ::: "memory");
    __syncthreads();

    // ---- S = Q K^T (D-layout: row=(lane>>4)*4+r, col=lane&15)
    f32x4 accS[2][4] = {};
    {
      bf16x8 Kf[4][2];
#pragma unroll
      for (int nf=0;nf<4;++nf){
        int row = nf*16 + (lane&15);
#pragma unroll
        for (int ks=0;ks<2;++ks){
          int ch = ((lane>>4) + ks*4) ^ (row&7);
          Kf[nf][ks] = *(const bf16x8*)(Kb_s + row*64 + ch*8);
        }
      }
#pragma unroll
      for (int mi=0;mi<2;++mi)
#pragma unroll
        for (int nf=0;nf<4;++nf){
          accS[mi][nf] = __builtin_amdgcn_mfma_f32_16x16x32_bf16(Qf[mi][0], Kf[nf][0], accS[mi][nf], 0,0,0);
          accS[mi][nf] = __builtin_amdgcn_mfma_f32_16x16x32_bf16(Qf[mi][1], Kf[nf][1], accS[mi][nf], 0,0,0);
        }
    }

    // ---- mask + scale (in place), step row-max
    float smax[2][4];
#pragma unroll
    for (int mi=0;mi<2;++mi)
#pragma unroll
      for (int r=0;r<4;++r) smax[mi][r] = -3e38f;
#pragma unroll
    for (int mi=0;mi<2;++mi)
#pragma unroll
      for (int nf=0;nf<4;++nf)
#pragma unroll
        for (int r=0;r<4;++r){
          int dd = (kb + nf*16 + (lane&15)) - (qpb + mi*16 + r);
          bool ok = (dd <= 256) && (dd >= -256);
          float v = ok ? accS[mi][nf][r]*0.125f : -3e38f;
          accS[mi][nf][r] = v;
          smax[mi][r] = fmaxf(smax[mi][r], v);
        }
#pragma unroll
    for (int mi=0;mi<2;++mi)
#pragma unroll
      for (int r=0;r<4;++r){
        float v = smax[mi][r];
        v = fmaxf(v, __shfl_xor(v,1,64)); v = fmaxf(v, __shfl_xor(v,2,64));
        v = fmaxf(v, __shfl_xor(v,4,64)); v = fmaxf(v, __shfl_xor(v,8,64));
        smax[mi][r] = v;
      }

    // ---- online update: P=exp(S-mn), O*=exp(mold-mn), write P to LDS (bf16)
#pragma unroll
    for (int mi=0;mi<2;++mi)
#pragma unroll
      for (int r=0;r<4;++r){
        float mn = fmaxf(mrun[mi][r], smax[mi][r]);
        float sc = __expf(mrun[mi][r] - mn);           // 0 if mrun=-inf & mn finite; 1 if both -inf
        float ls = 0.f;
#pragma unroll
        for (int nf=0;nf<4;++nf){
          float sv = accS[mi][nf][r];
          float p = (sv > -1e37f) ? __expf(sv - mn) : 0.f;
          accS[mi][nf][r] = p;
          ls += p;
        }
        ls += __shfl_xor(ls,1,64); ls += __shfl_xor(ls,2,64);
        ls += __shfl_xor(ls,4,64); ls += __shfl_xor(ls,8,64);
        lrun[mi][r] = lrun[mi][r]*sc + ls;
        mrun[mi][r] = mn;
#pragma unroll
        for (int df=0;df<4;++df) accO[mi][df][r] *= sc;
      }
    // P store: q_local = mi*16+(lane>>4)*4+r, k = nf*16+(lane&15)
#pragma unroll
    for (int mi=0;mi<2;++mi)
#pragma unroll
      for (int nf=0;nf<4;++nf)
#pragma unroll
        for (int r=0;r<4;++r){
          int ql = mi*16 + ((lane>>4)<<2) + r;
          int k  = nf*16 + (lane&15);
          int ch = (k>>3) ^ (ql&7);
          Pb_s[wv*2048 + ql*64 + ch*8 + (k&7)] = f2b(accS[mi][nf][r]);
        }
    asm volatile("s_waitcnt lgkmcnt(0)" ::: "memory");
    __builtin_amdgcn_sched_barrier(0);

    // ---- O += P V  (A=P from Pbuf, B=V^T from Vbuf)
    {
      bf16x8 Pf[2][2], Vf[4][2];
#pragma unroll
      for (int mi=0;mi<2;++mi){
        int ql = mi*16 + (lane&15);
#pragma unroll
        for (int ks=0;ks<2;++ks){
          int ch = ((lane>>4) + ks*4) ^ (ql&7);
          Pf[mi][ks] = *(const bf16x8*)(Pb_s + wv*2048 + ql*64 + ch*8);
        }
      }
#pragma unroll
      for (int df=0;df<4;++df){
        int dr = df*16 + (lane&15);
#pragma unroll
        for (int ks=0;ks<2;++ks){
          int ch = ((lane>>4) + ks*4) ^ (dr&7);
          Vf[df][ks] = *(const bf16x8*)(Vb_s + dr*64 + ch*8);
        }
      }
#pragma unroll
      for (int mi=0;mi<2;++mi)
#pragma unroll
        for (int df=0;df<4;++df){
          accO[mi][df] = __builtin_amdgcn_mfma_f32_16x16x32_bf16(Pf[mi][0], Vf[df][0], accO[mi][df], 0,0,0);
          accO[mi][df] = __builtin_amdgcn_mfma_f32_16x16x32_bf16(Pf[mi][1], Vf[df][1], accO[mi][df], 0,0,0);
        }
    }
    __syncthreads();   // all waves done reading K/V before next stage
  }

  // ---- epilogue: O /= l, write bf16
#pragma unroll
  for (int mi=0;mi<2;++mi)
#pragma unroll
    for (int df=0;df<4;++df)
#pragma unroll
      for (int r=0;r<4;++r){
        long long row = rowbase + qpb + mi*16 + r;
        int col = h*DH + df*16 + (lane&15);
        Om[row*DM + col] = f2b(accO[mi][df][r] / lrun[mi][r]);
      }
}

// ---------------- pointwise / small kernels ----------------
__global__ __launch_bounds__(256) void embed_ln_k(const int* __restrict__ x,
    const float* __restrict__ emb, const float* __restrict__ pos,
    const float* __restrict__ g, const float* __restrict__ bta,
    float* __restrict__ of, u16* __restrict__ ob)
{
  __shared__ float sm[4];
  const int row = blockIdx.x, s = row & (SL-1);
  const long long tok = x[row];
  const float* e = emb + tok*DM;
  const float* p = pos + (long long)s*DM;
  float v[3], su=0.f, sq=0.f;
#pragma unroll
  for (int i=0;i<3;++i){ int d=threadIdx.x+i*256; v[i]=e[d]+p[d]; su+=v[i]; sq+=v[i]*v[i]; }
  su = bred_sum(su, sm); sq = bred_sum(sq, sm);
  float mean = su*(1.f/DM), var = sq*(1.f/DM)-mean*mean, rs = rsqrtf(var+1e-5f);
#pragma unroll
  for (int i=0;i<3;++i){ int d=threadIdx.x+i*256;
    float o = (v[i]-mean)*rs*g[d] + bta[d];
    of[(long long)row*DM+d]=o; ob[(long long)row*DM+d]=f2b(o); }
}

__global__ __launch_bounds__(256) void resid_ln_k(const float* __restrict__ a, const float* __restrict__ c,
    const float* __restrict__ g, const float* __restrict__ bta,
    float* __restrict__ of, u16* __restrict__ ob)
{
  __shared__ float sm[4];
  const long long row = blockIdx.x;
  const float* ra = a + row*DM;
  const float* rc = c + row*DM;
  float v[3], su=0.f, sq=0.f;
#pragma unroll
  for (int i=0;i<3;++i){ int d=threadIdx.x+i*256; v[i]=ra[d]+rc[d]; su+=v[i]; sq+=v[i]*v[i]; }
  su = bred_sum(su, sm); sq = bred_sum(sq, sm);
  float mean = su*(1.f/DM), var = sq*(1.f/DM)-mean*mean, rs = rsqrtf(var+1e-5f);
#pragma unroll
  for (int i=0;i<3;++i){ int d=threadIdx.x+i*256;
    float o = (v[i]-mean)*rs*g[d] + bta[d];
    of[row*DM+d]=o; if (ob) ob[row*DM+d]=f2b(o); }
}

// fp32 [Kd,Nd] -> bf16 [Nd,Kd]
__global__ __launch_bounds__(256) void transp_w_k(const float* __restrict__ W, u16* __restrict__ Wt, int Kd, int Nd)
{
  __shared__ float t[32][33];
  int n0 = blockIdx.x*32, k0 = blockIdx.y*32;
  int lx = threadIdx.x & 31, ly = threadIdx.x >> 5;
#pragma unroll
  for (int i=0;i<4;++i) t[ly+i*8][lx] = W[(long long)(k0+ly+i*8)*Nd + n0+lx];
  __syncthreads();
#pragma unroll
  for (int i=0;i<4;++i) Wt[(long long)(n0+ly+i*8)*Kd + k0+lx] = f2b(t[lx][ly+i*8]);
}

// bf16 [8192,Nc] -> bf16 [B][Nc][SL]
__global__ __launch_bounds__(256) void transp_b_k(const u16* __restrict__ in, u16* __restrict__ out, int Nc)
{
  __shared__ u16 t[32][33];
  int c0 = blockIdx.x*32, r0 = blockIdx.y*32;
  int lx = threadIdx.x & 31, ly = threadIdx.x >> 5;
#pragma unroll
  for (int i=0;i<4;++i) t[ly+i*8][lx] = in[(long long)(r0+ly+i*8)*Nc + c0+lx];
  __syncthreads();
  int b = r0 >> 11, s0 = r0 & (SL-1);
#pragma unroll
  for (int i=0;i<4;++i) out[((long long)b*Nc + c0+ly+i*8)*SL + s0+lx] = t[lx][ly+i*8];
}

// outer-MHA softmax, in-place on bf16 scores (pre-scaled) [z][2048][2048]; key mask x!=0
__global__ __launch_bounds__(256) void mha_softmax_k(u16* __restrict__ sc, const int* __restrict__ x)
{
  __shared__ float sm[4];
  const int rid = blockIdx.x;
  const int qi = rid & (SL-1);
  const int z  = rid >> 11;
  const int b  = z >> 2;
  u16* row = sc + (long long)z*SL*SL + (long long)qi*SL;
  const int* xb = x + b*SL;
  float v[8]; float mx = -3e38f;
#pragma unroll
  for (int i=0;i<8;++i){
    int j = threadIdx.x + i*256;
    bool ok = xb[j] != 0;
    v[i] = ok ? b2f(row[j]) : -3e38f;
    mx = fmaxf(mx, v[i]);
  }
  mx = bred_max(mx, sm);
  float s = 0.f;
#pragma unroll
  for (int i=0;i<8;++i){ v[i] = (v[i] > -1e37f) ? __expf(v[i]-mx) : 0.f; s += v[i]; }
  s = bred_sum(s, sm);
  float inv = 1.f/s;
#pragma unroll
  for (int i=0;i<8;++i){ int j = threadIdx.x + i*256; row[j] = f2b(v[i]*inv); }
}

__global__ __launch_bounds__(256) void pool_part_k(const float* __restrict__ f, float* __restrict__ pp)
{
  int b = blockIdx.x, ch = blockIdx.y;
  float m0=-3e38f, m1=-3e38f, m2=-3e38f;
  for (int s = ch*128; s < ch*128+128; ++s){
    const float* r = f + ((long long)b*SL + s)*DM;
    m0=fmaxf(m0,r[threadIdx.x]); m1=fmaxf(m1,r[threadIdx.x+256]); m2=fmaxf(m2,r[threadIdx.x+512]);
  }
  float* o = pp + (long long)(b*16+ch)*DM;
  o[threadIdx.x]=m0; o[threadIdx.x+256]=m1; o[threadIdx.x+512]=m2;
}

__global__ __launch_bounds__(256) void pool_red_k(const float* __restrict__ pp, float* __restrict__ out)
{
  int b = blockIdx.x;
#pragma unroll
  for (int i=0;i<3;++i){
    int d = threadIdx.x + i*256;
    float m = -3e38f;
    for (int c=0;c<16;++c) m = fmaxf(m, pp[(long long)(b*16+c)*DM + d]);
    out[(long long)b*DM + d] = m;
  }
}

// ---------------- orchestration ----------------
extern "C" void kernel_launch(void* const* d_in, const int* in_sizes, int n_in,
                              void* d_out, int out_size, void* d_ws, size_t ws_size,
                              hipStream_t stream)
{
  const int*   x      = (const int*)  d_in[0];
  const float* emb    = (const float*)d_in[1];
  const float* pos    = (const float*)d_in[2];
  const float* ln_e_g = (const float*)d_in[3];
  const float* ln_e_b = (const float*)d_in[4];
  const float* lf_wq  = (const float*)d_in[5];
  const float* lf_wk  = (const float*)d_in[6];
  const float* lf_wv  = (const float*)d_in[7];
  const float* lf_wo  = (const float*)d_in[8];
  const float* ln1_g  = (const float*)d_in[9];
  const float* ln1_b  = (const float*)d_in[10];
  const float* w1     = (const float*)d_in[11];
  const float* w2     = (const float*)d_in[12];
  const float* ln2_g  = (const float*)d_in[13];
  const float* ln2_b  = (const float*)d_in[14];
  const float* mha_wq = (const float*)d_in[15];
  const float* mha_wk = (const float*)d_in[16];
  const float* mha_wv = (const float*)d_in[17];
  const float* mha_fc = (const float*)d_in[18];
  const float* mha_ln_g = (const float*)d_in[19];
  const float* mha_ln_b = (const float*)d_in[20];

  (void)hipFuncSetAttribute((const void*)gemm256_k<0,1>, hipFuncAttributeMaxDynamicSharedMemorySize, 131072);
  (void)hipFuncSetAttribute((const void*)gemm256_k<0,2>, hipFuncAttributeMaxDynamicSharedMemorySize, 131072);
  (void)hipFuncSetAttribute((const void*)gemm256_k<1,3>, hipFuncAttributeMaxDynamicSharedMemorySize, 131072);
  (void)hipFuncSetAttribute((const void*)gemm256_k<2,1>, hipFuncAttributeMaxDynamicSharedMemorySize, 131072);

  const long long R = 8192;           // B*S rows
  float* F0 = (float*)d_ws;           // h / out_lf (fp32)
  float* F1 = F0 + R*DM;              // gemm fp32 out
  float* F2 = F1 + R*DM;              // h2 / final ln
  u16* B0 = (u16*)(F2 + R*DM);        // h bf16 -> attn-out bf16
  u16* B1 = B0 + R*DM;                // q  -> h2 bf16
  u16* B2 = B1 + R*DM;                // k  -> out_lf bf16
  u16* B3 = B2 + R*DM;                // v^T [B][768][SL]
  u16* WT = B3 + R*DM;                // transposed weight scratch (bf16, max 3072x768)
  u16* G1 = WT + (long long)DFF*DM;   // gelu-out -> q_mha -> o_mha
  u16* G2 = G1 + R*DFF;               // k_mha
  u16* G3 = G2 + R*DFF;               // v_mha^T [B][3072][SL]
  u16* SC = G3 + R*DFF;               // scores scratch; also v row-major temp
  float* PP = (float*)(SC + (long long)4*12*NC*CC*768);  // pool partials

  dim3 T(256), T5(512);
  const size_t SMEM = 131072;
  // ---- longformer layer
  embed_ln_k<<<dim3(8192), T, 0, stream>>>(x, emb, pos, ln_e_g, ln_e_b, F0, B0);

  transp_w_k<<<dim3(24,24), T, 0, stream>>>(lf_wq, WT, DM, DM);
  gemm_k<128,128,0,1><<<dim3(64,6), T, 0, stream>>>(B0, WT, nullptr, B1, DM, DM, DM, DM);
  transp_w_k<<<dim3(24,24), T, 0, stream>>>(lf_wk, WT, DM, DM);
  gemm_k<128,128,0,1><<<dim3(64,6), T, 0, stream>>>(B0, WT, nullptr, B2, DM, DM, DM, DM);
  transp_w_k<<<dim3(24,24), T, 0, stream>>>(lf_wv, WT, DM, DM);
  gemm_k<128,128,0,1><<<dim3(64,6), T, 0, stream>>>(B0, WT, nullptr, SC, DM, DM, DM, DM);
  transp_b_k<<<dim3(24,256), T, 0, stream>>>(SC, B3, DM);

  sw_attn_k<<<dim3(16,12,4), T, 0, stream>>>(B1, B2, B3, B0);

  transp_w_k<<<dim3(24,24), T, 0, stream>>>(lf_wo, WT, DM, DM);
  gemm_k<128,128,0,0><<<dim3(64,6), T, 0, stream>>>(B0, WT, F1, nullptr, DM, DM, DM, DM);
  resid_ln_k<<<dim3(8192), T, 0, stream>>>(F0, F1, ln1_g, ln1_b, F2, B1);

  transp_w_k<<<dim3(96,24), T, 0, stream>>>(w1, WT, DM, DFF);
  gemm256_k<0,2><<<dim3(32,12,1), T5, SMEM, stream>>>(B1, WT, nullptr, G1, DM, DM, DM, DFF);
  transp_w_k<<<dim3(24,96), T, 0, stream>>>(w2, WT, DFF, DM);
  gemm_k<128,128,0,0><<<dim3(64,6), T, 0, stream>>>(G1, WT, F1, nullptr, DFF, DFF, DFF, DM);
  resid_ln_k<<<dim3(8192), T, 0, stream>>>(F2, F1, ln2_g, ln2_b, F0, B2);

  // ---- outer MHA
  transp_w_k<<<dim3(96,24), T, 0, stream>>>(mha_wq, WT, DM, DFF);
  gemm256_k<0,1><<<dim3(32,12,1), T5, SMEM, stream>>>(B2, WT, nullptr, G1, DM, DM, DM, DFF);
  transp_w_k<<<dim3(96,24), T, 0, stream>>>(mha_wk, WT, DM, DFF);
  gemm256_k<0,1><<<dim3(32,12,1), T5, SMEM, stream>>>(B2, WT, nullptr, G2, DM, DM, DM, DFF);
  transp_w_k<<<dim3(96,24), T, 0, stream>>>(mha_wv, WT, DM, DFF);
  gemm256_k<0,1><<<dim3(32,12,1), T5, SMEM, stream>>>(B2, WT, nullptr, SC, DM, DM, DM, DFF);
  transp_b_k<<<dim3(96,256), T, 0, stream>>>(SC, G3, DFF);

  gemm256_k<1,3><<<dim3(8,8,16), T5, SMEM, stream>>>(G1, G2, nullptr, SC, DKM, 3072, 3072, 0);
  mha_softmax_k<<<dim3(32768), T, 0, stream>>>(SC, x);
  gemm256_k<2,1><<<dim3(8,3,16), T5, SMEM, stream>>>(SC, G3, nullptr, G1, SL, SL, SL, 0);

  transp_w_k<<<dim3(24,96), T, 0, stream>>>(mha_fc, WT, DFF, DM);
  gemm_k<128,128,0,0><<<dim3(64,6), T, 0, stream>>>(G1, WT, F1, nullptr, DFF, DFF, DFF, DM);
  resid_ln_k<<<dim3(8192), T, 0, stream>>>(F0, F1, mha_ln_g, mha_ln_b, F2, nullptr);

  pool_part_k<<<dim3(4,16), T, 0, stream>>>(F2, PP);
  pool_red_k<<<dim3(4), T, 0, stream>>>(PP, (float*)d_out);
}

// Round 5
// 926.635 us; speedup vs baseline: 1.3324x; 1.1218x over previous
//
#include <hip/hip_runtime.h>
#include <hip/hip_bf16.h>
#include <math.h>

#define DEV static __device__ __forceinline__

typedef unsigned short u16;
typedef __attribute__((ext_vector_type(8))) __bf16 bf16x8;
typedef __attribute__((ext_vector_type(8))) unsigned short u16x8;
typedef __attribute__((ext_vector_type(4))) float f32x4;
typedef __attribute__((ext_vector_type(4))) int i32x4;

constexpr int SL  = 2048;   // seq len
constexpr int DM  = 768;    // d_model
constexpr int CC  = 256;    // chunk size = window
constexpr int DH  = 64;     // longformer head dim
constexpr int DFF = 3072;
constexpr int DKM = 768;    // outer-MHA head dim

DEV float b2f(u16 u){ union{float f; unsigned u;} c; c.u = ((unsigned)u)<<16; return c.f; }
DEV u16 f2b(float f){ union{float f; unsigned u;} c; c.f=f; unsigned r=(c.u + 0x7fffu + ((c.u>>16)&1u))>>16; return (u16)r; }

DEV void gld16(u16* lds, const u16* g){
  __builtin_amdgcn_global_load_lds((const __attribute__((address_space(1))) void*)g,
                                   (__attribute__((address_space(3))) void*)lds, 16, 0, 0);
}

// ---------------- reductions ----------------
DEV float wred_sum(float v){
#pragma unroll
  for (int o=32;o;o>>=1) v += __shfl_xor(v,o,64);
  return v;
}
DEV float wred_max(float v){
#pragma unroll
  for (int o=32;o;o>>=1) v = fmaxf(v, __shfl_xor(v,o,64));
  return v;
}
DEV float bred_sum(float v, float* sm){
  v = wred_sum(v);
  if ((threadIdx.x & 63)==0) sm[threadIdx.x>>6] = v;
  __syncthreads();
  float r = sm[0]+sm[1]+sm[2]+sm[3];
  __syncthreads();
  return r;
}

#define PHASE_SYNC \
  __builtin_amdgcn_s_barrier(); \
  asm volatile("s_waitcnt lgkmcnt(0)" ::: "memory"); \
  __builtin_amdgcn_sched_barrier(0); \
  __builtin_amdgcn_s_setprio(1);
#define PHASE_END \
  __builtin_amdgcn_s_setprio(0); \
  __builtin_amdgcn_s_barrier();

// ================= 256x256 8-phase BK=64 MFMA GEMM =================
// C = A[M,K] * Bt[N,K]^T, fp32 accum, bf16 inputs.
// MODE 0: dense.  1: MHA scores (z=(b,h)).  3: 3-way col scatter (3072 segs).
// EPI 0: fp32. 1: bf16. 2: fast-gelu+bf16. 3: *1/sqrt(768)+bf16.
#define MFMA_PH(MH, NH) \
  { _Pragma("unroll") for (int mi2=0; mi2<4; ++mi2) { \
      _Pragma("unroll") for (int ni2=0; ni2<2; ++ni2) { \
        acc[(MH)*4+mi2][(NH)*2+ni2] = __builtin_amdgcn_mfma_f32_16x16x32_bf16(Af[mi2][0], Bf[(NH)*2+ni2][0], acc[(MH)*4+mi2][(NH)*2+ni2], 0,0,0); \
        acc[(MH)*4+mi2][(NH)*2+ni2] = __builtin_amdgcn_mfma_f32_16x16x32_bf16(Af[mi2][1], Bf[(NH)*2+ni2][1], acc[(MH)*4+mi2][(NH)*2+ni2], 0,0,0); } } }

template<int MODE, int EPI>
__global__ __launch_bounds__(512,2) void gemm256_k(
    const u16* __restrict__ A, const u16* __restrict__ Bt,
    float* __restrict__ Cf, u16* __restrict__ Cb,
    u16* __restrict__ Cb2, u16* __restrict__ Cb3,
    int K, int lda, int ldb, int ldc)
{
  extern __shared__ u16 lds_dyn[];           // [2][256][64] A | [2][256][64] B
  const int tid = threadIdx.x, lane = tid & 63, wv = tid >> 6;
  const int wr = wv >> 2, wc = wv & 3;
  const int m0 = blockIdx.x * 256, n0 = blockIdx.y * 256, z = blockIdx.z;
  const int nt = K >> 6;

  int bb = 0, hh = 0;
  long long baseA = 0, baseB = 0;
  if constexpr (MODE==1) { bb=z>>2; hh=z&3; baseA=(long long)bb*SL*3072 + hh*DKM; baseB=baseA; }

  const int rb = (wv*64 + lane) >> 3;
  const int sg = ((lane & 7) ^ (rb & 7)) * 8;
  const int rd0 = (lane & 15)*64 + (((lane>>4) ^ (lane & 7)) * 8);
  const int rd1 = rd0 ^ 32;

  auto stageA = [&](int buf, int half, int kt) {
#pragma unroll
    for (int tt = 0; tt < 2; ++tt) {
      const int t = half + tt*2;             // INTERLEAVED halves: h0={0,2}, h1={1,3}
      gld16(lds_dyn + buf*16384 + t*4096 + wv*512,
            A + baseA + (long long)(m0 + t*64 + rb)*lda + (long long)kt*64 + sg);
    }
  };
  auto stageB = [&](int buf, int half, int kt) {
#pragma unroll
    for (int tt = 0; tt < 2; ++tt) {
      const int t = half*2 + tt;             // contiguous (all B reads finish by end of Q1)
      gld16(lds_dyn + 32768 + buf*16384 + t*4096 + wv*512,
            Bt + baseB + (long long)(n0 + t*64 + rb)*ldb + (long long)kt*64 + sg);
    }
  };

  f32x4 acc[8][4] = {};
  bf16x8 Af[4][2];
  bf16x8 Bf[4][2];

  stageA(0,0,0); stageB(0,0,0); stageB(0,1,0); stageA(0,1,0);
  stageA(1,0,1); stageB(1,0,1); stageB(1,1,1);
  asm volatile("s_waitcnt vmcnt(6)" ::: "memory");
  __builtin_amdgcn_s_barrier();

  for (int t = 0; t < nt; ++t) {
    const int d = t & 1;
    const u16* As_d = lds_dyn + d*16384;
    const u16* Bs_d = lds_dyn + 32768 + d*16384;
#pragma unroll
    for (int mi2=0; mi2<4; ++mi2) {
      const u16* p = As_d + (wr*128 + mi2*16)*64;
      Af[mi2][0] = *(const bf16x8*)(p + rd0);
      Af[mi2][1] = *(const bf16x8*)(p + rd1);
    }
#pragma unroll
    for (int ni2=0; ni2<2; ++ni2) {
      const u16* p = Bs_d + (wc*64 + ni2*16)*64;
      Bf[ni2][0] = *(const bf16x8*)(p + rd0);
      Bf[ni2][1] = *(const bf16x8*)(p + rd1);
    }
    if (t+1 < nt) stageA(d^1, 1, t+1);
    PHASE_SYNC; MFMA_PH(0,0); PHASE_END;
#pragma unroll
    for (int ni2=0; ni2<2; ++ni2) {
      const u16* p = Bs_d + (wc*64 + 32 + ni2*16)*64;
      Bf[2+ni2][0] = *(const bf16x8*)(p + rd0);
      Bf[2+ni2][1] = *(const bf16x8*)(p + rd1);
    }
    if (t+2 < nt) stageA(d, 0, t+2);
    PHASE_SYNC; MFMA_PH(0,1); PHASE_END;
#pragma unroll
    for (int mi2=0; mi2<4; ++mi2) {
      const u16* p = As_d + (wr*128 + 64 + mi2*16)*64;
      Af[mi2][0] = *(const bf16x8*)(p + rd0);
      Af[mi2][1] = *(const bf16x8*)(p + rd1);
    }
    if (t+2 < nt) stageB(d, 0, t+2);
    PHASE_SYNC; MFMA_PH(1,0); PHASE_END;
    if (t+2 < nt) stageB(d, 1, t+2);
    __builtin_amdgcn_s_barrier();
    __builtin_amdgcn_s_setprio(1);
    MFMA_PH(1,1);
    __builtin_amdgcn_s_setprio(0);
    if (t+2 < nt)      { asm volatile("s_waitcnt vmcnt(6)" ::: "memory"); }
    else if (t+1 < nt) { asm volatile("s_waitcnt vmcnt(0)" ::: "memory"); }
    __builtin_amdgcn_s_barrier();
  }

#pragma unroll
  for (int mi=0; mi<8; ++mi)
#pragma unroll
  for (int ni=0; ni<4; ++ni)
#pragma unroll
  for (int r=0; r<4; ++r) {
    int m = m0 + wr*128 + mi*16 + ((lane>>4)<<2) + r;
    int n = n0 + wc*64  + ni*16 + (lane & 15);
    float v = acc[mi][ni][r];
    if constexpr (EPI==2) {
      float u = 0.7978845608f*(v + 0.044715f*v*v*v);
      float th = 1.f - 2.f/(__expf(2.f*u)+1.f);
      v = 0.5f*v*(1.f + th);
    }
    if constexpr (EPI==3) v *= 0.0360843918f;   // 1/sqrt(768)
    if constexpr (MODE==3) {
      int seg = n / 3072, nn = n - seg*3072;
      u16* dst = seg==0 ? Cb : (seg==1 ? Cb2 : Cb3);
      dst[(long long)m*3072 + nn] = f2b(v);
    } else {
      long long ci;
      if constexpr (MODE==1) ci = (long long)z*SL*SL + (long long)m*SL + n;
      else                   ci = (long long)m*ldc + n;
      if constexpr (EPI==0) Cf[ci] = v; else Cb[ci] = f2b(v);
    }
  }
}

// ================= 256x128 8-phase BK=64 engine (MHA PV) =================
// C = P[z][SL][SL] * Vt[b][3072][SL]^T -> O[8192][3072] (per-head cols).
// 8 waves 4m x 2n; wave rows striped {mh*128 + wr*32 + mi2*16} so A stage
// half h = contiguous rows [h*128,(h+1)*128) == exactly phase mh's read set.
// vmcnt ledger: 6 issues/tile (A 2+2, B 1+1), counted vmcnt(4) at boundary.
#define MFMA_Q(MB, NB, AF) \
  { _Pragma("unroll") for (int mi2=0; mi2<2; ++mi2) { \
      _Pragma("unroll") for (int ni2=0; ni2<2; ++ni2) { \
        acc[(MB)+mi2][(NB)+ni2] = __builtin_amdgcn_mfma_f32_16x16x32_bf16(AF[mi2][0], Bf[(NB)+ni2][0], acc[(MB)+mi2][(NB)+ni2], 0,0,0); \
        acc[(MB)+mi2][(NB)+ni2] = __builtin_amdgcn_mfma_f32_16x16x32_bf16(AF[mi2][1], Bf[(NB)+ni2][1], acc[(MB)+mi2][(NB)+ni2], 0,0,0); } } }

__global__ __launch_bounds__(512,2) void gemm128n_k(
    const u16* __restrict__ A, const u16* __restrict__ Bt, u16* __restrict__ Cb, int K)
{
  extern __shared__ u16 lds_dyn[];           // A [2][256][64] @0 | B [2][128][64] @32768
  const int tid = threadIdx.x, lane = tid & 63, wv = tid >> 6;
  const int wr = wv >> 1, wc = wv & 1;
  const int m0 = blockIdx.x * 256, n0 = blockIdx.y * 128, z = blockIdx.z;
  const int bb = z >> 2, hh = z & 3;
  const long long baseA = (long long)z*SL*SL;
  const long long baseB = ((long long)bb*3072 + hh*DKM)*SL;
  const int nt = K >> 6;

  const int rb = (wv*64 + lane) >> 3;
  const int sg = ((lane & 7) ^ (rb & 7)) * 8;
  const int rd0 = (lane & 15)*64 + (((lane>>4) ^ (lane & 7)) * 8);
  const int rd1 = rd0 ^ 32;

  auto stageA = [&](int buf, int half, int kt) {
#pragma unroll
    for (int tt = 0; tt < 2; ++tt) {
      const int t = half*2 + tt;             // contiguous: h0 rows [0,128) == phase mh0 reads
      gld16(lds_dyn + buf*16384 + t*4096 + wv*512,
            A + baseA + (long long)(m0 + t*64 + rb)*SL + (long long)kt*64 + sg);
    }
  };
  auto stageB = [&](int buf, int idx, int kt) {
    gld16(lds_dyn + 32768 + buf*8192 + idx*4096 + wv*512,
          Bt + baseB + (long long)(n0 + idx*64 + rb)*SL + (long long)kt*64 + sg);
  };

  f32x4 acc[4][4] = {};
  bf16x8 Af[2][2];
  bf16x8 Bf[4][2];

  stageA(0,0,0); stageB(0,0,0); stageB(0,1,0); stageA(0,1,0);
  stageA(1,0,1); stageB(1,0,1); stageB(1,1,1);
  asm volatile("s_waitcnt vmcnt(4)" ::: "memory");
  __builtin_amdgcn_s_barrier();

  for (int t = 0; t < nt; ++t) {
    const int d = t & 1;
    const u16* As_d = lds_dyn + d*16384;
    const u16* Bs_d = lds_dyn + 32768 + d*8192;
    // Q0 reads: A mh0 (rows wr*32+mi2*16 within [0,128)), B nh0 (rows wc*64+ni2*16)
#pragma unroll
    for (int mi2=0; mi2<2; ++mi2) {
      const u16* p = As_d + (wr*32 + mi2*16)*64;
      Af[mi2][0] = *(const bf16x8*)(p + rd0);
      Af[mi2][1] = *(const bf16x8*)(p + rd1);
    }
#pragma unroll
    for (int ni2=0; ni2<2; ++ni2) {
      const u16* p = Bs_d + (wc*64 + ni2*16)*64;
      Bf[ni2][0] = *(const bf16x8*)(p + rd0);
      Bf[ni2][1] = *(const bf16x8*)(p + rd1);
    }
    if (t+1 < nt) stageA(d^1, 1, t+1);
    PHASE_SYNC; MFMA_Q(0,0,Af); PHASE_END;
    // Q1 reads: B nh1 (rows wc*64+32+ni2*16)
#pragma unroll
    for (int ni2=0; ni2<2; ++ni2) {
      const u16* p = Bs_d + (wc*64 + 32 + ni2*16)*64;
      Bf[2+ni2][0] = *(const bf16x8*)(p + rd0);
      Bf[2+ni2][1] = *(const bf16x8*)(p + rd1);
    }
    if (t+2 < nt) stageA(d, 0, t+2);
    PHASE_SYNC; MFMA_Q(0,2,Af); PHASE_END;
    // Q2 reads: A mh1 (rows 128 + wr*32 + mi2*16)
#pragma unroll
    for (int mi2=0; mi2<2; ++mi2) {
      const u16* p = As_d + (128 + wr*32 + mi2*16)*64;
      Af[mi2][0] = *(const bf16x8*)(p + rd0);
      Af[mi2][1] = *(const bf16x8*)(p + rd1);
    }
    if (t+2 < nt) stageB(d, 0, t+2);
    PHASE_SYNC; MFMA_Q(2,0,Af); PHASE_END;
    if (t+2 < nt) stageB(d, 1, t+2);
    __builtin_amdgcn_s_barrier();
    __builtin_amdgcn_s_setprio(1);
    MFMA_Q(2,2,Af);
    __builtin_amdgcn_s_setprio(0);
    if (t+2 < nt)      { asm volatile("s_waitcnt vmcnt(4)" ::: "memory"); }
    else if (t+1 < nt) { asm volatile("s_waitcnt vmcnt(0)" ::: "memory"); }
    __builtin_amdgcn_s_barrier();
  }

  // epilogue: m rows striped: m = m0 + (mi>>1)*128 + wr*32 + (mi&1)*16 + (lane>>4)*4 + r
#pragma unroll
  for (int mi=0; mi<4; ++mi)
#pragma unroll
  for (int ni=0; ni<4; ++ni)
#pragma unroll
  for (int r=0; r<4; ++r) {
    int m = m0 + (mi>>1)*128 + wr*32 + (mi&1)*16 + ((lane>>4)<<2) + r;
    int n = n0 + wc*64 + ni*16 + (lane & 15);
    Cb[((long long)bb*SL + m)*3072 + hh*DKM + n] = f2b(acc[mi][ni][r]);
  }
}

// ---------------- legacy 128x128 BK=32 GEMM ----------------
// MODE 0: dense.  5: 3-way col scatter (768 segs).
template<int BM, int BN, int MODE, int EPI>
__global__ __launch_bounds__(256) void gemm_k(
    const u16* __restrict__ A, const u16* __restrict__ Bt,
    float* __restrict__ Cf, u16* __restrict__ Cb,
    u16* __restrict__ Cb2, u16* __restrict__ Cb3,
    int K, int lda, int ldb, int ldc)
{
  constexpr int BK = 32;
  constexpr int WM = BM/2, WN = BN/2, FM = WM/16, FN = WN/16;
  __shared__ __attribute__((aligned(16))) u16 As[BM*BK];
  __shared__ __attribute__((aligned(16))) u16 Bs[BN*BK];
  const int tid = threadIdx.x, lane = tid & 63, wv = tid >> 6;
  const int wr = wv >> 1, wc = wv & 1;
  const int m0 = blockIdx.x * BM, n0 = blockIdx.y * BN;

  f32x4 acc[FM][FN] = {};

  for (int kt = 0; kt < K; kt += BK) {
#pragma unroll
    for (int t = 0; t < (BM*4)/256; ++t) {
      int cb  = (t*4 + wv)*64;
      int ch  = cb + lane;
      int row = ch >> 2, cp = ch & 3;
      int gp  = cp ^ (row & 3) ^ ((row >> 2) & 1);
      long long ga = (long long)(m0 + row)*lda + (kt + gp*8);
      gld16(&As[cb*8], A + ga);
    }
#pragma unroll
    for (int t = 0; t < (BN*4)/256; ++t) {
      int cb  = (t*4 + wv)*64;
      int ch  = cb + lane;
      int row = ch >> 2, cp = ch & 3;
      int gp  = cp ^ (row & 3) ^ ((row >> 2) & 1);
      long long gb = (long long)(n0 + row)*ldb + (kt + gp*8);
      gld16(&Bs[cb*8], Bt + gb);
    }
    __syncthreads();
    bf16x8 af[FM], bfr[FN];
#pragma unroll
    for (int mi=0; mi<FM; ++mi) {
      int row = wr*WM + mi*16 + (lane & 15);
      int cp  = (lane >> 4) ^ (row & 3) ^ ((row >> 2) & 1);
      af[mi] = *reinterpret_cast<const bf16x8*>(&As[row*BK + cp*8]);
    }
#pragma unroll
    for (int ni=0; ni<FN; ++ni) {
      int row = wc*WN + ni*16 + (lane & 15);
      int cp  = (lane >> 4) ^ (row & 3) ^ ((row >> 2) & 1);
      bfr[ni] = *reinterpret_cast<const bf16x8*>(&Bs[row*BK + cp*8]);
    }
#pragma unroll
    for (int mi=0; mi<FM; ++mi)
#pragma unroll
      for (int ni=0; ni<FN; ++ni)
        acc[mi][ni] = __builtin_amdgcn_mfma_f32_16x16x32_bf16(af[mi], bfr[ni], acc[mi][ni], 0,0,0);
    __syncthreads();
  }

#pragma unroll
  for (int mi=0; mi<FM; ++mi)
#pragma unroll
  for (int ni=0; ni<FN; ++ni)
#pragma unroll
  for (int r=0; r<4; ++r) {
    int m = m0 + wr*WM + mi*16 + ((lane>>4)<<2) + r;
    int n = n0 + wc*WN + ni*16 + (lane & 15);
    float v = acc[mi][ni][r];
    if constexpr (MODE==5) {
      int seg = n / 768, nn = n - seg*768;
      u16* dst = seg==0 ? Cb : (seg==1 ? Cb2 : Cb3);
      dst[(long long)m*768 + nn] = f2b(v);
    } else {
      long long ci = (long long)m*ldc + n;
      if constexpr (EPI==0) Cf[ci] = v; else Cb[ci] = f2b(v);
    }
  }
}

// ================= fused sliding-window attention =================
__global__ __launch_bounds__(256) void sw_attn_k(
    const u16* __restrict__ Qm, const u16* __restrict__ Km,
    const u16* __restrict__ Vt, u16* __restrict__ Om)
{
  __shared__ __attribute__((aligned(16))) u16 Kb_s[64*64];
  __shared__ __attribute__((aligned(16))) u16 Vb_s[64*64];
  __shared__ __attribute__((aligned(16))) u16 Pb_s[4*32*64];
  const int tid = threadIdx.x, lane = tid & 63, wv = tid >> 6;
  const int qc = blockIdx.x >> 1, half = blockIdx.x & 1;
  const int h = blockIdx.y, b = blockIdx.z;
  const int q0 = qc*256 + half*128 + wv*32;
  const long long rowbase = (long long)b*SL;

  bf16x8 Qf[2][2];
#pragma unroll
  for (int mi=0;mi<2;++mi)
#pragma unroll
    for (int ks=0;ks<2;++ks)
      Qf[mi][ks] = *(const bf16x8*)(Qm + (rowbase + q0 + mi*16 + (lane&15))*DM + h*DH + ks*32 + (lane>>4)*8);

  f32x4 accO[2][4] = {};
  float mrun[2][4], lrun[2][4];
#pragma unroll
  for (int mi=0;mi<2;++mi)
#pragma unroll
    for (int r=0;r<4;++r){ mrun[mi][r]=-3e38f; lrun[mi][r]=0.f; }

  const int srow = tid >> 3;
  const int schunk = (tid & 7) ^ (srow & 7);

  const int kb0 = qc*256 + half*128 - 256;
  const int slo = kb0 < 0 ? ((-kb0) >> 6) : 0;
  const int shi_t = (SL - kb0) >> 6;
  const int shi = shi_t < 10 ? shi_t : 10;

  const int qpb = q0 + ((lane>>4)<<2);

  for (int s = slo; s < shi; ++s) {
    const int kb = kb0 + s*64;
#pragma unroll
    for (int ii=0; ii<2; ++ii) {
      gld16(Kb_s + ii*2048 + wv*512,
            Km + (rowbase + kb + srow + ii*32)*DM + h*DH + schunk*8);
      gld16(Vb_s + ii*2048 + wv*512,
            Vt + ((long long)b*DM + h*DH + srow + ii*32)*SL + kb + schunk*8);
    }
    asm volatile("s_waitcnt vmcnt(0)" ::: "memory");
    __syncthreads();

    f32x4 accS[2][4] = {};
    {
      bf16x8 Kf[4][2];
#pragma unroll
      for (int nf=0;nf<4;++nf){
        int row = nf*16 + (lane&15);
#pragma unroll
        for (int ks=0;ks<2;++ks){
          int ch = ((lane>>4) + ks*4) ^ (row&7);
          Kf[nf][ks] = *(const bf16x8*)(Kb_s + row*64 + ch*8);
        }
      }
#pragma unroll
      for (int mi=0;mi<2;++mi)
#pragma unroll
        for (int nf=0;nf<4;++nf){
          accS[mi][nf] = __builtin_amdgcn_mfma_f32_16x16x32_bf16(Qf[mi][0], Kf[nf][0], accS[mi][nf], 0,0,0);
          accS[mi][nf] = __builtin_amdgcn_mfma_f32_16x16x32_bf16(Qf[mi][1], Kf[nf][1], accS[mi][nf], 0,0,0);
        }
    }

    float smax[2][4];
#pragma unroll
    for (int mi=0;mi<2;++mi)
#pragma unroll
      for (int r=0;r<4;++r) smax[mi][r] = -3e38f;
#pragma unroll
    for (int mi=0;mi<2;++mi)
#pragma unroll
      for (int nf=0;nf<4;++nf)
#pragma unroll
        for (int r=0;r<4;++r){
          int dd = (kb + nf*16 + (lane&15)) - (qpb + mi*16 + r);
          bool ok = (dd <= 256) && (dd >= -256);
          float v = ok ? accS[mi][nf][r]*0.125f : -3e38f;
          accS[mi][nf][r] = v;
          smax[mi][r] = fmaxf(smax[mi][r], v);
        }
#pragma unroll
    for (int mi=0;mi<2;++mi)
#pragma unroll
      for (int r=0;r<4;++r){
        float v = smax[mi][r];
        v = fmaxf(v, __shfl_xor(v,1,64)); v = fmaxf(v, __shfl_xor(v,2,64));
        v = fmaxf(v, __shfl_xor(v,4,64)); v = fmaxf(v, __shfl_xor(v,8,64));
        smax[mi][r] = v;
      }

#pragma unroll
    for (int mi=0;mi<2;++mi)
#pragma unroll
      for (int r=0;r<4;++r){
        float mn = fmaxf(mrun[mi][r], smax[mi][r]);
        float sc = __expf(mrun[mi][r] - mn);
        float ls = 0.f;
#pragma unroll
        for (int nf=0;nf<4;++nf){
          float sv = accS[mi][nf][r];
          float p = (sv > -1e37f) ? __expf(sv - mn) : 0.f;
          accS[mi][nf][r] = p;
          ls += p;
        }
        ls += __shfl_xor(ls,1,64); ls += __shfl_xor(ls,2,64);
        ls += __shfl_xor(ls,4,64); ls += __shfl_xor(ls,8,64);
        lrun[mi][r] = lrun[mi][r]*sc + ls;
        mrun[mi][r] = mn;
#pragma unroll
        for (int df=0;df<4;++df) accO[mi][df][r] *= sc;
      }
#pragma unroll
    for (int mi=0;mi<2;++mi)
#pragma unroll
      for (int nf=0;nf<4;++nf)
#pragma unroll
        for (int r=0;r<4;++r){
          int ql = mi*16 + ((lane>>4)<<2) + r;
          int k  = nf*16 + (lane&15);
          int ch = (k>>3) ^ (ql&7);
          Pb_s[wv*2048 + ql*64 + ch*8 + (k&7)] = f2b(accS[mi][nf][r]);
        }
    asm volatile("s_waitcnt lgkmcnt(0)" ::: "memory");
    __builtin_amdgcn_sched_barrier(0);

    {
      bf16x8 Pf[2][2], Vf[4][2];
#pragma unroll
      for (int mi=0;mi<2;++mi){
        int ql = mi*16 + (lane&15);
#pragma unroll
        for (int ks=0;ks<2;++ks){
          int ch = ((lane>>4) + ks*4) ^ (ql&7);
          Pf[mi][ks] = *(const bf16x8*)(Pb_s + wv*2048 + ql*64 + ch*8);
        }
      }
#pragma unroll
      for (int df=0;df<4;++df){
        int dr = df*16 + (lane&15);
#pragma unroll
        for (int ks=0;ks<2;++ks){
          int ch = ((lane>>4) + ks*4) ^ (dr&7);
          Vf[df][ks] = *(const bf16x8*)(Vb_s + dr*64 + ch*8);
        }
      }
#pragma unroll
      for (int mi=0;mi<2;++mi)
#pragma unroll
        for (int df=0;df<4;++df){
          accO[mi][df] = __builtin_amdgcn_mfma_f32_16x16x32_bf16(Pf[mi][0], Vf[df][0], accO[mi][df], 0,0,0);
          accO[mi][df] = __builtin_amdgcn_mfma_f32_16x16x32_bf16(Pf[mi][1], Vf[df][1], accO[mi][df], 0,0,0);
        }
    }
    __syncthreads();
  }

#pragma unroll
  for (int mi=0;mi<2;++mi)
#pragma unroll
    for (int df=0;df<4;++df)
#pragma unroll
      for (int r=0;r<4;++r){
        long long row = rowbase + qpb + mi*16 + r;
        int col = h*DH + df*16 + (lane&15);
        Om[row*DM + col] = f2b(accO[mi][df][r] / lrun[mi][r]);
      }
}

// ---------------- pointwise / small kernels ----------------
__global__ __launch_bounds__(256) void embed_ln_k(const int* __restrict__ x,
    const float* __restrict__ emb, const float* __restrict__ pos,
    const float* __restrict__ g, const float* __restrict__ bta,
    float* __restrict__ of, u16* __restrict__ ob)
{
  __shared__ float sm[4];
  const int row = blockIdx.x, s = row & (SL-1);
  const long long tok = x[row];
  const float* e = emb + tok*DM;
  const float* p = pos + (long long)s*DM;
  float v[3], su=0.f, sq=0.f;
#pragma unroll
  for (int i=0;i<3;++i){ int d=threadIdx.x+i*256; v[i]=e[d]+p[d]; su+=v[i]; sq+=v[i]*v[i]; }
  su = bred_sum(su, sm); sq = bred_sum(sq, sm);
  float mean = su*(1.f/DM), var = sq*(1.f/DM)-mean*mean, rs = rsqrtf(var+1e-5f);
#pragma unroll
  for (int i=0;i<3;++i){ int d=threadIdx.x+i*256;
    float o = (v[i]-mean)*rs*g[d] + bta[d];
    of[(long long)row*DM+d]=o; ob[(long long)row*DM+d]=f2b(o); }
}

__global__ __launch_bounds__(256) void resid_ln_k(const float* __restrict__ a, const float* __restrict__ c,
    const float* __restrict__ g, const float* __restrict__ bta,
    float* __restrict__ of, u16* __restrict__ ob)
{
  __shared__ float sm[4];
  const long long row = blockIdx.x;
  const float* ra = a + row*DM;
  const float* rc = c + row*DM;
  float v[3], su=0.f, sq=0.f;
#pragma unroll
  for (int i=0;i<3;++i){ int d=threadIdx.x+i*256; v[i]=ra[d]+rc[d]; su+=v[i]; sq+=v[i]*v[i]; }
  su = bred_sum(su, sm); sq = bred_sum(sq, sm);
  float mean = su*(1.f/DM), var = sq*(1.f/DM)-mean*mean, rs = rsqrtf(var+1e-5f);
#pragma unroll
  for (int i=0;i<3;++i){ int d=threadIdx.x+i*256;
    float o = (v[i]-mean)*rs*g[d] + bta[d];
    of[row*DM+d]=o; if (ob) ob[row*DM+d]=f2b(o); }
}

// fp32 [Kd,Nd] -> bf16 [Nd,Kd]
__global__ __launch_bounds__(256) void transp_w_k(const float* __restrict__ W, u16* __restrict__ Wt, int Kd, int Nd)
{
  __shared__ float t[32][33];
  int n0 = blockIdx.x*32, k0 = blockIdx.y*32;
  int lx = threadIdx.x & 31, ly = threadIdx.x >> 5;
#pragma unroll
  for (int i=0;i<4;++i) t[ly+i*8][lx] = W[(long long)(k0+ly+i*8)*Nd + n0+lx];
  __syncthreads();
#pragma unroll
  for (int i=0;i<4;++i) Wt[(long long)(n0+ly+i*8)*Kd + k0+lx] = f2b(t[lx][ly+i*8]);
}

// bf16 [8192,Nc] -> bf16 [B][Nc][SL]
__global__ __launch_bounds__(256) void transp_b_k(const u16* __restrict__ in, u16* __restrict__ out, int Nc)
{
  __shared__ u16 t[32][33];
  int c0 = blockIdx.x*32, r0 = blockIdx.y*32;
  int lx = threadIdx.x & 31, ly = threadIdx.x >> 5;
#pragma unroll
  for (int i=0;i<4;++i) t[ly+i*8][lx] = in[(long long)(r0+ly+i*8)*Nc + c0+lx];
  __syncthreads();
  int b = r0 >> 11, s0 = r0 & (SL-1);
#pragma unroll
  for (int i=0;i<4;++i) out[((long long)b*Nc + c0+ly+i*8)*SL + s0+lx] = t[lx][ly+i*8];
}

// outer-MHA softmax: one wave per row, in-place on pre-scaled bf16 scores
__global__ __launch_bounds__(256) void mha_softmax_k(u16* __restrict__ sc, const int* __restrict__ x)
{
  const int r = blockIdx.x*4 + (threadIdx.x >> 6);
  const int lane = threadIdx.x & 63;
  const int z = r >> 11;
  const int b = z >> 2;
  u16* row = sc + (long long)z*SL*SL + (long long)(r & (SL-1))*SL;
  const int* xb = x + b*SL;
  float v[32]; float mx = -3e38f;
#pragma unroll
  for (int i=0;i<4;++i){
    const int j0 = i*512 + lane*8;
    u16x8 pv = *(const u16x8*)(row + j0);
    i32x4 xa = *(const i32x4*)(xb + j0);
    i32x4 xc = *(const i32x4*)(xb + j0 + 4);
#pragma unroll
    for (int e=0;e<8;++e){
      int xv = e<4 ? xa[e] : xc[e-4];
      float f = (xv != 0) ? b2f(pv[e]) : -3e38f;
      v[i*8+e] = f;
      mx = fmaxf(mx, f);
    }
  }
  mx = wred_max(mx);
  float s = 0.f;
#pragma unroll
  for (int i=0;i<32;++i){ v[i] = (v[i] > -1e37f) ? __expf(v[i]-mx) : 0.f; s += v[i]; }
  s = wred_sum(s);
  float inv = 1.f/s;
#pragma unroll
  for (int i=0;i<4;++i){
    u16x8 ov;
#pragma unroll
    for (int e=0;e<8;++e) ov[e] = f2b(v[i*8+e]*inv);
    *(u16x8*)(row + i*512 + lane*8) = ov;
  }
}

__global__ __launch_bounds__(256) void pool_part_k(const float* __restrict__ f, float* __restrict__ pp)
{
  int b = blockIdx.x, ch = blockIdx.y;
  float m0=-3e38f, m1=-3e38f, m2=-3e38f;
  for (int s = ch*128; s < ch*128+128; ++s){
    const float* r = f + ((long long)b*SL + s)*DM;
    m0=fmaxf(m0,r[threadIdx.x]); m1=fmaxf(m1,r[threadIdx.x+256]); m2=fmaxf(m2,r[threadIdx.x+512]);
  }
  float* o = pp + (long long)(b*16+ch)*DM;
  o[threadIdx.x]=m0; o[threadIdx.x+256]=m1; o[threadIdx.x+512]=m2;
}

__global__ __launch_bounds__(256) void pool_red_k(const float* __restrict__ pp, float* __restrict__ out)
{
  int b = blockIdx.x;
#pragma unroll
  for (int i=0;i<3;++i){
    int d = threadIdx.x + i*256;
    float m = -3e38f;
    for (int c=0;c<16;++c) m = fmaxf(m, pp[(long long)(b*16+c)*DM + d]);
    out[(long long)b*DM + d] = m;
  }
}

// ---------------- orchestration ----------------
extern "C" void kernel_launch(void* const* d_in, const int* in_sizes, int n_in,
                              void* d_out, int out_size, void* d_ws, size_t ws_size,
                              hipStream_t stream)
{
  const int*   x      = (const int*)  d_in[0];
  const float* emb    = (const float*)d_in[1];
  const float* pos    = (const float*)d_in[2];
  const float* ln_e_g = (const float*)d_in[3];
  const float* ln_e_b = (const float*)d_in[4];
  const float* lf_wq  = (const float*)d_in[5];
  const float* lf_wk  = (const float*)d_in[6];
  const float* lf_wv  = (const float*)d_in[7];
  const float* lf_wo  = (const float*)d_in[8];
  const float* ln1_g  = (const float*)d_in[9];
  const float* ln1_b  = (const float*)d_in[10];
  const float* w1     = (const float*)d_in[11];
  const float* w2     = (const float*)d_in[12];
  const float* ln2_g  = (const float*)d_in[13];
  const float* ln2_b  = (const float*)d_in[14];
  const float* mha_wq = (const float*)d_in[15];
  const float* mha_wk = (const float*)d_in[16];
  const float* mha_wv = (const float*)d_in[17];
  const float* mha_fc = (const float*)d_in[18];
  const float* mha_ln_g = (const float*)d_in[19];
  const float* mha_ln_b = (const float*)d_in[20];

  (void)hipFuncSetAttribute((const void*)gemm256_k<0,2>, hipFuncAttributeMaxDynamicSharedMemorySize, 131072);
  (void)hipFuncSetAttribute((const void*)gemm256_k<1,3>, hipFuncAttributeMaxDynamicSharedMemorySize, 131072);
  (void)hipFuncSetAttribute((const void*)gemm256_k<3,1>, hipFuncAttributeMaxDynamicSharedMemorySize, 131072);
  (void)hipFuncSetAttribute((const void*)gemm128n_k,     hipFuncAttributeMaxDynamicSharedMemorySize, 98304);

  const long long R = 8192;           // B*S rows
  float* F0 = (float*)d_ws;           // h / out_lf (fp32)
  float* F1 = F0 + R*DM;              // gemm fp32 out
  float* F2 = F1 + R*DM;              // h2 / final ln
  u16* B0 = (u16*)(F2 + R*DM);        // h bf16 -> attn-out bf16
  u16* B1 = B0 + R*DM;                // lf q -> h2 bf16
  u16* B2 = B1 + R*DM;                // lf k -> out_lf bf16
  u16* B3 = B2 + R*DM;                // lf v^T [B][768][SL]
  u16* WT = B3 + R*DM;                // transposed weights (bf16, up to 9216x768)
  u16* G1 = WT + (long long)9216*DM;  // gelu-out / mha q
  u16* G2 = G1 + R*DFF;               // mha k -> mha o
  u16* G3 = G2 + R*DFF;               // mha v^T [B][3072][SL]
  u16* SC = G3 + R*DFF;               // lf v temp / mha v temp / mha P (134MB)
  float* PP = (float*)(SC + (long long)16*SL*SL);   // pool partials

  dim3 T(256), T5(512);
  const size_t SM256 = 131072, SM128 = 98304;

  // ---- longformer layer
  embed_ln_k<<<dim3(8192), T, 0, stream>>>(x, emb, pos, ln_e_g, ln_e_b, F0, B0);

  // fused lf qkv: WT = [q|k|v]^T (2304x768), scatter -> B1,B2,SC
  transp_w_k<<<dim3(24,24), T, 0, stream>>>(lf_wq, WT,               DM, DM);
  transp_w_k<<<dim3(24,24), T, 0, stream>>>(lf_wk, WT + 768*768,     DM, DM);
  transp_w_k<<<dim3(24,24), T, 0, stream>>>(lf_wv, WT + 2*768*768,   DM, DM);
  gemm_k<128,128,5,1><<<dim3(64,18), T, 0, stream>>>(B0, WT, nullptr, B1, B2, SC, DM, DM, DM, 0);
  transp_b_k<<<dim3(24,256), T, 0, stream>>>(SC, B3, DM);

  sw_attn_k<<<dim3(16,12,4), T, 0, stream>>>(B1, B2, B3, B0);

  transp_w_k<<<dim3(24,24), T, 0, stream>>>(lf_wo, WT, DM, DM);
  gemm_k<128,128,0,0><<<dim3(64,6), T, 0, stream>>>(B0, WT, F1, nullptr, nullptr, nullptr, DM, DM, DM, DM);
  resid_ln_k<<<dim3(8192), T, 0, stream>>>(F0, F1, ln1_g, ln1_b, F2, B1);

  transp_w_k<<<dim3(96,24), T, 0, stream>>>(w1, WT, DM, DFF);
  gemm256_k<0,2><<<dim3(32,12,1), T5, SM256, stream>>>(B1, WT, nullptr, G1, nullptr, nullptr, DM, DM, DM, DFF);
  transp_w_k<<<dim3(24,96), T, 0, stream>>>(w2, WT, DFF, DM);
  gemm_k<128,128,0,0><<<dim3(64,6), T, 0, stream>>>(G1, WT, F1, nullptr, nullptr, nullptr, DFF, DFF, DFF, DM);
  resid_ln_k<<<dim3(8192), T, 0, stream>>>(F2, F1, ln2_g, ln2_b, F0, B2);

  // ---- outer MHA: fused qkv (WT = [wq|wk|wv]^T 9216x768), scatter -> G1,G2,SC
  transp_w_k<<<dim3(96,24), T, 0, stream>>>(mha_wq, WT,                 DM, DFF);
  transp_w_k<<<dim3(96,24), T, 0, stream>>>(mha_wk, WT + (long long)3072*768, DM, DFF);
  transp_w_k<<<dim3(96,24), T, 0, stream>>>(mha_wv, WT + (long long)6144*768, DM, DFF);
  gemm256_k<3,1><<<dim3(32,36,1), T5, SM256, stream>>>(B2, WT, nullptr, G1, G2, SC, DM, DM, DM, 0);
  transp_b_k<<<dim3(96,256), T, 0, stream>>>(SC, G3, DFF);

  gemm256_k<1,3><<<dim3(8,8,16), T5, SM256, stream>>>(G1, G2, nullptr, SC, nullptr, nullptr, DKM, 3072, 3072, 0);
  mha_softmax_k<<<dim3(8192), T, 0, stream>>>(SC, x);
  gemm128n_k<<<dim3(8,6,16), T5, SM128, stream>>>(SC, G3, G2, SL);

  transp_w_k<<<dim3(24,96), T, 0, stream>>>(mha_fc, WT, DFF, DM);
  gemm_k<128,128,0,0><<<dim3(64,6), T, 0, stream>>>(G2, WT, F1, nullptr, nullptr, nullptr, DFF, DFF, DFF, DM);
  resid_ln_k<<<dim3(8192), T, 0, stream>>>(F0, F1, mha_ln_g, mha_ln_b, F2, nullptr);

  pool_part_k<<<dim3(4,16), T, 0, stream>>>(F2, PP);
  pool_red_k<<<dim3(4), T, 0, stream>>>(PP, (float*)d_out);
}